// Round 13
// baseline (1580.167 us; speedup 1.0000x reference)
//
#include <hip/hip_runtime.h>
#include <math.h>

// ---------------- problem constants ----------------
#define NB   16

// d_out float offsets
#define O_P1 0
#define O_F1 (16*3*1024)            // 49152
#define O_P2 (O_F1 + 16*128*1024)   // 2146304
#define O_F2 (O_P2 + 16*3*256)      // 2158592

// workspace byte offsets
#define WS_GIDX1 0
#define WS_GIDX2 (WS_GIDX1 + 16*1024*32*4)
#define WS_W1T   (WS_GIDX2 + 16*256*64*4)
#define WS_W2T   (WS_W1T  + 6*64*4)
#define WS_W3T   (WS_W2T  + 64*64*4)
#define WS_W20T  (WS_W3T  + 64*128*4)
#define WS_W21T  (WS_W20T + 131*128*4)
#define WS_W22T  (WS_W21T + 128*128*4)
#define WS_PTS4  (WS_W22T + 128*256*4)        // float4[16][4096] packed (x,y,z,|p|^2)
#define WS_P14   (WS_PTS4 + 16*4096*16)       // float4[16][1024] packed p1

#define DEVINL __device__ __forceinline__
typedef unsigned long long u64;

DEVINL float4 f4fma(float w, float4 v, float4 a) {
    a.x = fmaf(w, v.x, a.x); a.y = fmaf(w, v.y, a.y);
    a.z = fmaf(w, v.z, a.z); a.w = fmaf(w, v.w, a.w);
    return a;
}
DEVINL float4 f4relub(float4 a, float b) {
    float4 r;
    r.x = fmaxf(a.x + b, 0.f); r.y = fmaxf(a.y + b, 0.f);
    r.z = fmaxf(a.z + b, 0.f); r.w = fmaxf(a.w + b, 0.f);
    return r;
}
DEVINL float f4max(float4 a) { return fmaxf(fmaxf(a.x, a.y), fmaxf(a.z, a.w)); }

// order-preserving float -> uint mapping (monotone increasing)
DEVINL unsigned fkey(float f) {
    unsigned u = __float_as_uint(f);
    return (u & 0x80000000u) ? ~u : (u | 0x80000000u);
}

DEVINL u64 shflx64(u64 v, int m) {
    unsigned lo = __shfl_xor((unsigned)v, m);
    unsigned hi = __shfl_xor((unsigned)(v >> 32), m);
    return ((u64)hi << 32) | lo;
}

// inclusive add-scan within wave64. Canonical masks: bcast15 -> rows 1&3 (0xA),
// bcast31 -> rows 2&3 (0xC).
template<int CTRL, int RMASK>
DEVINL unsigned dpp_addstep(unsigned v) {
    unsigned t = (unsigned)__builtin_amdgcn_update_dpp(0, (int)v, CTRL, RMASK, 0xF, true);
    return v + t;
}
DEVINL unsigned wave_scan_add(unsigned v) {
    v = dpp_addstep<0x111, 0xF>(v);
    v = dpp_addstep<0x112, 0xF>(v);
    v = dpp_addstep<0x114, 0xF>(v);
    v = dpp_addstep<0x118, 0xF>(v);
    v = dpp_addstep<0x142, 0xA>(v);
    v = dpp_addstep<0x143, 0xC>(v);
    return v;
}

// ---------------- shared-memory layouts ----------------
template<int N, int NP> struct __align__(16) FpsS {      // 4-wave FPS (fps1)
    float4 spts[N];
    int sel[NP];
    u64 rbuf[2][4];
};
template<int N, int NP> struct __align__(16) FpsWS {     // 1-wave FPS (fps2) ~17.4KB
    float4 spts[N];
    int sel[NP];
};
struct __align__(16) KnnS {                              // keyless: ~16.4KB -> 8 blk/CU
    unsigned hist[2048];
    unsigned ckey[1024];
    int      cidx[1024];
    unsigned wpart[4];
    unsigned sbin, sKb, scnt, cntL;
};
struct __align__(16) Mlp1S {                             // ~44KB
    float sw1[6*64], sw2[64*64];
    float sb1[64], sb2[64], sb3[128];
    float sx[6*32], sh1[64*36], sh2[64*36];
    float spm[128*4], sout[128*8];
    int   sgi[32];
    float sq[3];
};

// ---------------- weight transpose + BN-gamma fold (device impl) ----------------
DEVINL void prep_impl(int e0,
    const float* __restrict__ w10, const float* __restrict__ g10,
    const float* __restrict__ w11, const float* __restrict__ g11,
    const float* __restrict__ w12, const float* __restrict__ g12,
    const float* __restrict__ w20, const float* __restrict__ g20,
    const float* __restrict__ w21, const float* __restrict__ g21,
    const float* __restrict__ w22, const float* __restrict__ g22,
    float* __restrict__ w1t, float* __restrict__ w2t, float* __restrict__ w3t,
    float* __restrict__ w20t, float* __restrict__ w21t, float* __restrict__ w22t)
{
    if (e0 < 384)  { int o = e0/6,   i = e0%6;   w1t [i*64  + o] = w10[e0]*g10[o]; return; }
    e0 -= 384;
    if (e0 < 4096) { int o = e0/64,  i = e0%64;  w2t [i*64  + o] = w11[e0]*g11[o]; return; }
    e0 -= 4096;
    if (e0 < 8192) { int o = e0/64,  i = e0%64;  w3t [i*128 + o] = w12[e0]*g12[o]; return; }
    e0 -= 8192;
    if (e0 < 16768){ int o = e0/131, i = e0%131; w20t[i*128 + o] = w20[e0]*g20[o]; return; }
    e0 -= 16768;
    if (e0 < 16384){ int o = e0/128, i = e0%128; w21t[i*128 + o] = w21[e0]*g21[o]; return; }
    e0 -= 16384;
    if (e0 < 32768){ int o = e0/128, i = e0%128; w22t[i*256 + o] = w22[e0]*g22[o]; return; }
}

// ---------------- FPS 4-wave (R8 structure; exact jnp semantics) ----------------
template<int N, int NP>
DEVINL void fps_impl(FpsS<N, NP>& sm, const float* __restrict__ pts,
                     float* __restrict__ prop, int b, float4* pack_out)
{
    constexpr int NT = 256;
    constexpr int PT = N / NT;
    int tid = threadIdx.x;
    const float* p = pts + (size_t)b * 3 * N;
    for (int n = tid; n < N; n += NT) {
        float x = p[n], y = p[N+n], z = p[2*N+n];
        sm.spts[n] = make_float4(x, y, z, 0.f);
        if (pack_out) {
            float s = __fadd_rn(__fadd_rn(__fmul_rn(x,x), __fmul_rn(y,y)), __fmul_rn(z,z));
            pack_out[(size_t)b*N + n] = make_float4(x, y, z, s);
        }
    }
    __syncthreads();

    float lx[PT], ly[PT], lz[PT], ld[PT];
    int base = tid * PT;
#pragma unroll
    for (int j = 0; j < PT; ++j) {
        float4 q = sm.spts[base+j];
        lx[j] = q.x; ly[j] = q.y; lz[j] = q.z;
        ld[j] = __builtin_inff();
    }
    if (tid == 0) sm.sel[0] = 0;
    float4 qp = sm.spts[0];
    for (int s = 1; s < NP; ++s) {
        float qx = qp.x, qy = qp.y, qz = qp.z;
        float bd = -1.0f; int bi = 0x7FFFFFFF;
#pragma unroll
        for (int j = 0; j < PT; ++j) {
            float dx = __fsub_rn(lx[j], qx);
            float dy = __fsub_rn(ly[j], qy);
            float dz = __fsub_rn(lz[j], qz);
            float dd = __fadd_rn(__fadd_rn(__fmul_rn(dx,dx), __fmul_rn(dy,dy)), __fmul_rn(dz,dz));
            float v = fminf(ld[j], dd);
            ld[j] = v;
            if (v > bd) { bd = v; bi = base + j; }   // ascending j -> lowest idx on tie
        }
        u64 pk = ((u64)__float_as_uint(bd) << 32) | (unsigned)(~bi);
#pragma unroll
        for (int mk = 1; mk < 64; mk <<= 1) {
            u64 o = shflx64(pk, mk);
            if (o > pk) pk = o;
        }
        if ((tid & 63) == 0) sm.rbuf[s & 1][tid >> 6] = pk;
        __syncthreads();
        u64 g = sm.rbuf[s & 1][0];
#pragma unroll
        for (int w = 1; w < 4; ++w) { u64 o = sm.rbuf[s & 1][w]; if (o > g) g = o; }
        int last = (int)(~(unsigned)g);
        qp = sm.spts[last];
        if (tid == 0) sm.sel[s] = last;
    }
    __syncthreads();
    for (int m = tid; m < NP; m += NT) {
        float4 q = sm.spts[sm.sel[m]];
        prop[(size_t)b*3*NP + m]        = q.x;
        prop[(size_t)b*3*NP + NP + m]   = q.y;
        prop[(size_t)b*3*NP + 2*NP + m] = q.z;
    }
}

// ---------------- FPS single-wave (fps2: N=1024) ----------------
// One wave: no barrier, no slot round-trip, no cross-wave reduce — the xor
// butterfly leaves the max in ALL lanes, so `last` is known immediately.
// Load+pack phase uses all 256 threads; threads >=64 exit after the one barrier.
template<int N, int NP>
DEVINL void fps_wave_impl(FpsWS<N, NP>& sm, const float* __restrict__ pts,
                          float* __restrict__ prop, int b, float4* pack_out)
{
    constexpr int PT = N / 64;
    int tid = threadIdx.x;
    const float* p = pts + (size_t)b * 3 * N;
    for (int n = tid; n < N; n += 256) {
        float x = p[n], y = p[N+n], z = p[2*N+n];
        sm.spts[n] = make_float4(x, y, z, 0.f);
        if (pack_out) {
            float s = __fadd_rn(__fadd_rn(__fmul_rn(x,x), __fmul_rn(y,y)), __fmul_rn(z,z));
            pack_out[(size_t)b*N + n] = make_float4(x, y, z, s);
        }
    }
    __syncthreads();
    if (tid >= 64) return;

    int lane = tid;
    float lx[PT], ly[PT], lz[PT], ld[PT];
    int base = lane * PT;
#pragma unroll
    for (int j = 0; j < PT; ++j) {
        float4 q = sm.spts[base+j];
        lx[j] = q.x; ly[j] = q.y; lz[j] = q.z;
        ld[j] = __builtin_inff();
    }
    if (lane == 0) sm.sel[0] = 0;
    float4 qp = sm.spts[0];
    for (int s = 1; s < NP; ++s) {
        float qx = qp.x, qy = qp.y, qz = qp.z;
        float bd = -1.0f; int bi = 0x7FFFFFFF;
#pragma unroll
        for (int j = 0; j < PT; ++j) {
            float dx = __fsub_rn(lx[j], qx);
            float dy = __fsub_rn(ly[j], qy);
            float dz = __fsub_rn(lz[j], qz);
            float dd = __fadd_rn(__fadd_rn(__fmul_rn(dx,dx), __fmul_rn(dy,dy)), __fmul_rn(dz,dz));
            float v = fminf(ld[j], dd);
            ld[j] = v;
            if (v > bd) { bd = v; bi = base + j; }   // ascending j -> lowest idx on tie
        }
        u64 pk = ((u64)__float_as_uint(bd) << 32) | (unsigned)(~bi);
#pragma unroll
        for (int mk = 1; mk < 64; mk <<= 1) {
            u64 o = shflx64(pk, mk);
            if (o > pk) pk = o;
        }
        int last = (int)(~(unsigned)pk);             // all lanes hold the max
        qp = sm.spts[last];                          // broadcast read
        if (lane == 0) sm.sel[s] = last;
    }
    for (int m = lane; m < NP; m += 64) {
        float4 q = sm.spts[sm.sel[m]];
        prop[(size_t)b*3*NP + m]        = q.x;
        prop[(size_t)b*3*NP + NP + m]   = q.y;
        prop[(size_t)b*3*NP + 2*NP + m] = q.z;
    }
}

// ---------------- KNN keyless (packed points, recompute pass 2): 11-bit select ----
// Exact K smallest by (dist, idx) lexicographic order; output order arbitrary
// (downstream max-pool is permutation-invariant). 16.4KB LDS -> 8 blocks/CU.
template<int N, int K, int M>
DEVINL void knn_impl(KnnS& sm, const float4* __restrict__ pts4,
                     const float* __restrict__ qry, int* __restrict__ gidx, int bm)
{
    int tid = threadIdx.x, lane = tid & 63, wid = tid >> 6;
    int b = bm / M, m = bm % M;
    const float4* p4 = pts4 + (size_t)b * N;
    float qx = qry[(size_t)b*3*M + m];
    float qy = qry[(size_t)b*3*M + M + m];
    float qz = qry[(size_t)b*3*M + 2*M + m];
    float sqq = __fadd_rn(__fadd_rn(__fmul_rn(qx,qx), __fmul_rn(qy,qy)), __fmul_rn(qz,qz));

    for (int e = tid; e < 2048; e += 256) sm.hist[e] = 0;
    if (tid == 0) { sm.scnt = 0; sm.cntL = 0; sm.sbin = 2047u; sm.sKb = 0; }
    __syncthreads();
    // pass 1: distances from packed points + 11-bit histogram
    for (int n = tid; n < N; n += 256) {
        float4 pp = p4[n];
        float dot = __fadd_rn(__fadd_rn(__fmul_rn(qx,pp.x), __fmul_rn(qy,pp.y)), __fmul_rn(qz,pp.z));
        float d = __fadd_rn(__fsub_rn(sqq, __fmul_rn(2.0f, dot)), pp.w);
        atomicAdd(&sm.hist[fkey(d) >> 21], 1u);
    }
    __syncthreads();
    // locate bin containing the K-th smallest + count strictly before it
    unsigned hloc[8], s8 = 0;
#pragma unroll
    for (int j = 0; j < 8; ++j) { hloc[j] = sm.hist[tid*8 + j]; s8 += hloc[j]; }
    unsigned sc = wave_scan_add(s8);
    if (lane == 63) sm.wpart[wid] = sc;
    __syncthreads();
    unsigned woff = 0;
    for (int w = 0; w < wid; ++w) woff += sm.wpart[w];
    unsigned cumEnd = sc + woff;
    unsigned cbase = cumEnd - s8;
    if ((unsigned)K > cbase && (unsigned)K <= cumEnd) {
        unsigned run = cbase;
#pragma unroll
        for (int j = 0; j < 8; ++j) {
            if ((unsigned)K > run && (unsigned)K <= run + hloc[j]) { sm.sbin = (unsigned)(tid*8 + j); sm.sKb = run; }
            run += hloc[j];
        }
    }
    __syncthreads();
    unsigned bin1 = sm.sbin;
    unsigned Kb   = sm.sKb;     // # keys with prefix < bin1 (all selected)
    int* gout = gidx + ((size_t)b * M + m) * K;
    // pass 2: recompute keys (bit-identical), emit winners, compact boundary bin
    for (int n = tid; n < N; n += 256) {
        float4 pp = p4[n];
        float dot = __fadd_rn(__fadd_rn(__fmul_rn(qx,pp.x), __fmul_rn(qy,pp.y)), __fmul_rn(qz,pp.z));
        float d = __fadd_rn(__fsub_rn(sqq, __fmul_rn(2.0f, dot)), pp.w);
        unsigned k = fkey(d), pfx = k >> 21;
        if (pfx < bin1) {
            unsigned pos = atomicAdd(&sm.cntL, 1u);
            if (pos < (unsigned)K) gout[pos] = n;
        } else if (pfx == bin1) {
            unsigned pos = atomicAdd(&sm.scnt, 1u);
            if (pos < 1024u) { sm.ckey[pos] = k; sm.cidx[pos] = n; }
        }
    }
    __syncthreads();
    int cnt = (int)sm.scnt; if (cnt > 1024) cnt = 1024;
    int need = K - (int)Kb;
    if (tid < 64) {
        for (int c = lane; c < cnt; c += 64) {
            unsigned mk = sm.ckey[c]; int mi = sm.cidx[c];
            int rank = 0;
            for (int l = 0; l < cnt; ++l) {
                unsigned ok = sm.ckey[l];
                rank += (ok < mk || (ok == mk && sm.cidx[l] < mi)) ? 1 : 0;
            }
            if (rank < need && (int)Kb + rank < K) gout[Kb + rank] = mi;
        }
    }
}

// ---------------- layer-1 MLP device impl (sw3 de-staged, ~44KB LDS) ----------------
DEVINL void mlp1_impl(Mlp1S& sm,
    const float* __restrict__ pts,   // [B,3,4096]
    const float* __restrict__ q,     // points1 [B,3,1024]
    const int*   __restrict__ gidx,  // [B,1024,32]
    const float* __restrict__ w1t, const float* __restrict__ w2t, const float* __restrict__ w3t,
    const float* __restrict__ b1, const float* __restrict__ b2, const float* __restrict__ b3,
    float* __restrict__ out, int blk)         // feats1 [B,128,1024]
{
    int tid = threadIdx.x;
    for (int e = tid; e < 6*64;   e += 256) sm.sw1[e] = w1t[e];
    for (int e = tid; e < 64*64;  e += 256) sm.sw2[e] = w2t[e];
    if (tid < 64) { sm.sb1[tid] = b1[tid]; sm.sb2[tid] = b2[tid]; }
    else if (tid < 192) sm.sb3[tid-64] = b3[tid-64];

    int pid0 = blk * 8;
    int b = pid0 >> 10, m0 = pid0 & 1023;
    int c = tid & 63, kq = tid >> 6, kb = kq * 8;
    __syncthreads();

    for (int it = 0; it < 8; ++it) {
        int m = m0 + it;
        if (tid < 32) sm.sgi[tid] = gidx[((size_t)b*1024 + m)*32 + tid];
        else if (tid < 35) sm.sq[tid-32] = q[((size_t)b*3 + (tid-32))*1024 + m];
        __syncthreads();
        if (tid < 192) {
            int cc = tid >> 5, k = tid & 31;
            int gi = sm.sgi[k];
            const float* pb = pts + (size_t)b*3*4096;
            float v = (cc < 3) ? (pb[cc*4096 + gi] - sm.sq[cc]) : pb[(cc-3)*4096 + gi];
            sm.sx[cc*32 + k] = v;
        }
        __syncthreads();
        // L1: 6 -> 64
        float4 a0 = make_float4(0,0,0,0), a1 = make_float4(0,0,0,0);
#pragma unroll
        for (int i = 0; i < 6; ++i) {
            float w = sm.sw1[i*64 + c];
            a0 = f4fma(w, *(const float4*)&sm.sx[i*32 + kb],     a0);
            a1 = f4fma(w, *(const float4*)&sm.sx[i*32 + kb + 4], a1);
        }
        {
            float bias = sm.sb1[c];
            *(float4*)&sm.sh1[c*36 + kb]     = f4relub(a0, bias);
            *(float4*)&sm.sh1[c*36 + kb + 4] = f4relub(a1, bias);
        }
        __syncthreads();
        // L2: 64 -> 64
        a0 = make_float4(0,0,0,0); a1 = make_float4(0,0,0,0);
#pragma unroll 4
        for (int i = 0; i < 64; ++i) {
            float w = sm.sw2[i*64 + c];
            a0 = f4fma(w, *(const float4*)&sm.sh1[i*36 + kb],     a0);
            a1 = f4fma(w, *(const float4*)&sm.sh1[i*36 + kb + 4], a1);
        }
        {
            float bias = sm.sb2[c];
            *(float4*)&sm.sh2[c*36 + kb]     = f4relub(a0, bias);
            *(float4*)&sm.sh2[c*36 + kb + 4] = f4relub(a1, bias);
        }
        __syncthreads();
        // L3: 64 -> 128 (2 channels/thread), weights straight from L2
        float4 aA0 = make_float4(0,0,0,0), aA1 = make_float4(0,0,0,0);
        float4 aB0 = make_float4(0,0,0,0), aB1 = make_float4(0,0,0,0);
#pragma unroll 4
        for (int i = 0; i < 64; ++i) {
            float wA = w3t[i*128 + c], wB = w3t[i*128 + c + 64];
            float4 v0 = *(const float4*)&sm.sh2[i*36 + kb];
            float4 v1 = *(const float4*)&sm.sh2[i*36 + kb + 4];
            aA0 = f4fma(wA, v0, aA0); aA1 = f4fma(wA, v1, aA1);
            aB0 = f4fma(wB, v0, aB0); aB1 = f4fma(wB, v1, aB1);
        }
        float mA = fmaxf(fmaxf(f4max(aA0), f4max(aA1)) + sm.sb3[c],      0.f);
        float mB = fmaxf(fmaxf(f4max(aB0), f4max(aB1)) + sm.sb3[c + 64], 0.f);
        sm.spm[c*4 + kq]        = mA;
        sm.spm[(c + 64)*4 + kq] = mB;
        __syncthreads();
        if (tid < 128) {
            float f = fmaxf(fmaxf(sm.spm[tid*4], sm.spm[tid*4+1]), fmaxf(sm.spm[tid*4+2], sm.spm[tid*4+3]));
            sm.sout[tid*8 + it] = f;
        }
        __syncthreads();
    }
    for (int e = tid; e < 128*8; e += 256) {
        int cc = e >> 3, j = e & 7;
        out[((size_t)b*128 + cc)*1024 + m0 + j] = sm.sout[e];
    }
}

// ---------------- fused kernels ----------------
// K1: fps1 (0..15) || prep_weights (16..322) || pack pts4 (323..386)
__global__ __launch_bounds__(256) void fused1(
    const float* __restrict__ pts, float* __restrict__ p1, float4* __restrict__ pts4,
    const float* w10, const float* g10, const float* w11, const float* g11,
    const float* w12, const float* g12, const float* w20, const float* g20,
    const float* w21, const float* g21, const float* w22, const float* g22,
    float* w1t, float* w2t, float* w3t, float* w20t, float* w21t, float* w22t)
{
    __shared__ FpsS<4096, 1024> sm;
    if (blockIdx.x < 16) {
        fps_impl<4096, 1024>(sm, pts, p1, blockIdx.x, nullptr);
    } else if (blockIdx.x < 323) {
        prep_impl((blockIdx.x - 16) * 256 + threadIdx.x,
                  w10, g10, w11, g11, w12, g12, w20, g20, w21, g21, w22, g22,
                  w1t, w2t, w3t, w20t, w21t, w22t);
    } else {
        int pblk = blockIdx.x - 323;   // 0..63, 1024 points each
#pragma unroll
        for (int i = 0; i < 4; ++i) {
            int idx = pblk * 1024 + i * 256 + threadIdx.x;
            int b = idx >> 12, n = idx & 4095;
            const float* p = pts + (size_t)b * 3 * 4096;
            float x = p[n], y = p[4096 + n], z = p[2*4096 + n];
            float s = __fadd_rn(__fadd_rn(__fmul_rn(x,x), __fmul_rn(y,y)), __fmul_rn(z,z));
            pts4[idx] = make_float4(x, y, z, s);
        }
    }
}

// K2: fps2 1-wave (0..15, writes packed p14) || knn1 (16..16399, 8 blocks/CU)
union SmemK2 { FpsWS<1024, 256> fps; KnnS knn; };
__global__ __launch_bounds__(256) void fused2(
    const float4* __restrict__ pts4, const float* __restrict__ p1,
    float* __restrict__ p2, int* __restrict__ gidx1, float4* __restrict__ p14)
{
    __shared__ SmemK2 sm;
    if (blockIdx.x < 16) {
        fps_wave_impl<1024, 256>(sm.fps, p1, p2, blockIdx.x, p14);
    } else {
        knn_impl<4096, 32, 1024>(sm.knn, pts4, p1, gidx1, blockIdx.x - 16);
    }
}

// K3: mlp1 (0..2047) || knn2 (2048..6143)
union SmemK3 { Mlp1S mlp; KnnS knn; };
__global__ __launch_bounds__(256) void fused3(
    const float* __restrict__ pts, const float* __restrict__ p1,
    const int* __restrict__ gidx1,
    const float* __restrict__ w1t, const float* __restrict__ w2t, const float* __restrict__ w3t,
    const float* __restrict__ b1, const float* __restrict__ b2, const float* __restrict__ b3,
    float* __restrict__ f1,
    const float4* __restrict__ p14, const float* __restrict__ p2, int* __restrict__ gidx2)
{
    __shared__ SmemK3 sm;
    if (blockIdx.x < 2048) {
        mlp1_impl(sm.mlp, pts, p1, gidx1, w1t, w2t, w3t, b1, b2, b3, f1, blockIdx.x);
    } else {
        knn_impl<1024, 64, 256>(sm.knn, p14, p2, gidx2, blockIdx.x - 2048);
    }
}

// ---------------- K4: mlp2 gather + MLP(131->128->128->256) + maxpool(64) ----------
__global__ __launch_bounds__(256, 4) void mlp2_kernel(
    const float* __restrict__ p1,   // [B,3,1024]
    const float* __restrict__ f1,   // [B,128,1024]
    const float* __restrict__ q2,   // [B,3,256]
    const int*   __restrict__ gidx, // [B,256,64]
    const float* __restrict__ w20t, const float* __restrict__ w21t, const float* __restrict__ w22t,
    const float* __restrict__ b20, const float* __restrict__ b21, const float* __restrict__ b22,
    float* __restrict__ out)        // feats2 [B,256,256]
{
    __shared__ __align__(16) float xb[131*68];   // x -> h1 -> h2 (ping-pong in place)
    __shared__ float spm[256*2];
    __shared__ int   sgi[64];
    __shared__ float sq[3];

    int tid = threadIdx.x;
    int b = blockIdx.x >> 8, m = blockIdx.x & 255;
    if (tid < 64) sgi[tid] = gidx[((size_t)b*256 + m)*64 + tid];
    else if (tid < 67) sq[tid-64] = q2[((size_t)b*3 + (tid-64))*256 + m];
    __syncthreads();
    for (int e = tid; e < 131*64; e += 256) {
        int i = e >> 6, k = e & 63;
        int gi = sgi[k];
        float v = (i < 3) ? (p1[((size_t)b*3 + i)*1024 + gi] - sq[i])
                          : f1[((size_t)b*128 + (i-3))*1024 + gi];
        xb[i*68 + k] = v;
    }
    __syncthreads();

    int c = tid & 127, kq = tid >> 7, kb = kq * 32;
    // L1: 131 -> 128
    float4 acc[8];
#pragma unroll
    for (int j = 0; j < 8; ++j) acc[j] = make_float4(0,0,0,0);
#pragma unroll 4
    for (int i = 0; i < 131; ++i) {
        float w = w20t[i*128 + c];
        const float4* xv = (const float4*)&xb[i*68 + kb];
#pragma unroll
        for (int j = 0; j < 8; ++j) acc[j] = f4fma(w, xv[j], acc[j]);
    }
    __syncthreads();
    {
        float bias = b20[c];
        float4* hv = (float4*)&xb[c*68 + kb];
#pragma unroll
        for (int j = 0; j < 8; ++j) hv[j] = f4relub(acc[j], bias);
    }
    __syncthreads();
    // L2: 128 -> 128
#pragma unroll
    for (int j = 0; j < 8; ++j) acc[j] = make_float4(0,0,0,0);
#pragma unroll 4
    for (int i = 0; i < 128; ++i) {
        float w = w21t[i*128 + c];
        const float4* xv = (const float4*)&xb[i*68 + kb];
#pragma unroll
        for (int j = 0; j < 8; ++j) acc[j] = f4fma(w, xv[j], acc[j]);
    }
    __syncthreads();
    {
        float bias = b21[c];
        float4* hv = (float4*)&xb[c*68 + kb];
#pragma unroll
        for (int j = 0; j < 8; ++j) hv[j] = f4relub(acc[j], bias);
    }
    __syncthreads();
    // L3: 128 -> 256 (2 channels/thread), maxpool over this thread's 32 k
    float4 aA[8], aB[8];
#pragma unroll
    for (int j = 0; j < 8; ++j) { aA[j] = make_float4(0,0,0,0); aB[j] = make_float4(0,0,0,0); }
#pragma unroll 2
    for (int i = 0; i < 128; ++i) {
        float wA = w22t[i*256 + c], wB = w22t[i*256 + c + 128];
        const float4* xv = (const float4*)&xb[i*68 + kb];
#pragma unroll
        for (int j = 0; j < 8; ++j) {
            float4 v = xv[j];
            aA[j] = f4fma(wA, v, aA[j]);
            aB[j] = f4fma(wB, v, aB[j]);
        }
    }
    float mxA = -__builtin_inff(), mxB = -__builtin_inff();
#pragma unroll
    for (int j = 0; j < 8; ++j) { mxA = fmaxf(mxA, f4max(aA[j])); mxB = fmaxf(mxB, f4max(aB[j])); }
    float mA = fmaxf(mxA + b22[c],       0.f);
    float mB = fmaxf(mxB + b22[c + 128], 0.f);
    spm[c*2 + kq]         = mA;
    spm[(c + 128)*2 + kq] = mB;
    __syncthreads();
    {
        float f = fmaxf(spm[tid*2], spm[tid*2 + 1]);
        out[((size_t)b*256 + tid)*256 + m] = f;
    }
}

// ---------------- launch ----------------
extern "C" void kernel_launch(void* const* d_in, const int* in_sizes, int n_in,
                              void* d_out, int out_size, void* d_ws, size_t ws_size,
                              hipStream_t stream)
{
    const float* pts = (const float*)d_in[0];
    const float* w10 = (const float*)d_in[1];
    const float* g10 = (const float*)d_in[2];
    const float* b10 = (const float*)d_in[3];
    const float* w11 = (const float*)d_in[4];
    const float* g11 = (const float*)d_in[5];
    const float* b11 = (const float*)d_in[6];
    const float* w12 = (const float*)d_in[7];
    const float* g12 = (const float*)d_in[8];
    const float* b12 = (const float*)d_in[9];
    const float* w20 = (const float*)d_in[10];
    const float* g20 = (const float*)d_in[11];
    const float* b20 = (const float*)d_in[12];
    const float* w21 = (const float*)d_in[13];
    const float* g21 = (const float*)d_in[14];
    const float* b21 = (const float*)d_in[15];
    const float* w22 = (const float*)d_in[16];
    const float* g22 = (const float*)d_in[17];
    const float* b22 = (const float*)d_in[18];

    float* out = (float*)d_out;
    char* ws = (char*)d_ws;
    int* gidx1 = (int*)(ws + WS_GIDX1);
    int* gidx2 = (int*)(ws + WS_GIDX2);
    float* w1t  = (float*)(ws + WS_W1T);
    float* w2t  = (float*)(ws + WS_W2T);
    float* w3t  = (float*)(ws + WS_W3T);
    float* w20t = (float*)(ws + WS_W20T);
    float* w21t = (float*)(ws + WS_W21T);
    float* w22t = (float*)(ws + WS_W22T);
    float4* pts4 = (float4*)(ws + WS_PTS4);
    float4* p14  = (float4*)(ws + WS_P14);

    float* p1 = out + O_P1;   // [16,3,1024]
    float* f1 = out + O_F1;   // [16,128,1024]
    float* p2 = out + O_P2;   // [16,3,256]
    float* f2 = out + O_F2;   // [16,256,256]

    // K1: fps1 || prep_weights || pack pts4
    fused1<<<16 + 307 + 64, 256, 0, stream>>>(pts, p1, pts4,
                                              w10, g10, w11, g11, w12, g12,
                                              w20, g20, w21, g21, w22, g22,
                                              w1t, w2t, w3t, w20t, w21t, w22t);
    // K2: fps2 (1-wave, packs p14) || knn1 (keyless, 8 blocks/CU)
    fused2<<<16 + NB * 1024, 256, 0, stream>>>(pts4, p1, p2, gidx1, p14);
    // K3: mlp1 || knn2
    fused3<<<2048 + NB * 256, 256, 0, stream>>>(pts, p1, gidx1,
                                                w1t, w2t, w3t, b10, b11, b12, f1,
                                                p14, p2, gidx2);
    // K4: mlp2
    mlp2_kernel<<<NB * 256, 256, 0, stream>>>(p1, f1, p2, gidx2,
                                              w20t, w21t, w22t, b20, b21, b22, f2);
}

// Round 14
// 1255.768 us; speedup vs baseline: 1.2583x; 1.2583x over previous
//
#include <hip/hip_runtime.h>
#include <math.h>

// ---------------- problem constants ----------------
#define NB   16

// d_out float offsets
#define O_P1 0
#define O_F1 (16*3*1024)            // 49152
#define O_P2 (O_F1 + 16*128*1024)   // 2146304
#define O_F2 (O_P2 + 16*3*256)      // 2158592

// workspace byte offsets
#define WS_GIDX1 0
#define WS_GIDX2 (WS_GIDX1 + 16*1024*32*4)
#define WS_W1T   (WS_GIDX2 + 16*256*64*4)
#define WS_W2T   (WS_W1T  + 6*64*4)
#define WS_W3T   (WS_W2T  + 64*64*4)
#define WS_W1H   (WS_W3T  + 64*128*4)         // fp16 [128][160]
#define WS_W2H   (WS_W1H  + 128*160*2)        // fp16 [128][128]
#define WS_W3H   (WS_W2H  + 128*128*2)        // fp16 [256][128]
#define WS_PTS4  (WS_W3H  + 256*128*2)        // float4[16][4096] (x,y,z,|p|^2)
#define WS_P14   (WS_PTS4 + 16*4096*16)       // float4[16][1024] packed p1

#define DEVINL __device__ __forceinline__
typedef unsigned long long u64;
typedef _Float16 f16x8 __attribute__((ext_vector_type(8)));
typedef float f32x4 __attribute__((ext_vector_type(4)));

DEVINL float4 f4fma(float w, float4 v, float4 a) {
    a.x = fmaf(w, v.x, a.x); a.y = fmaf(w, v.y, a.y);
    a.z = fmaf(w, v.z, a.z); a.w = fmaf(w, v.w, a.w);
    return a;
}
DEVINL float4 f4relub(float4 a, float b) {
    float4 r;
    r.x = fmaxf(a.x + b, 0.f); r.y = fmaxf(a.y + b, 0.f);
    r.z = fmaxf(a.z + b, 0.f); r.w = fmaxf(a.w + b, 0.f);
    return r;
}
DEVINL float f4max(float4 a) { return fmaxf(fmaxf(a.x, a.y), fmaxf(a.z, a.w)); }

// order-preserving float -> uint mapping (monotone increasing)
DEVINL unsigned fkey(float f) {
    unsigned u = __float_as_uint(f);
    return (u & 0x80000000u) ? ~u : (u | 0x80000000u);
}

DEVINL u64 shflx64(u64 v, int m) {
    unsigned lo = __shfl_xor((unsigned)v, m);
    unsigned hi = __shfl_xor((unsigned)(v >> 32), m);
    return ((u64)hi << 32) | lo;
}

// inclusive add-scan within wave64. Canonical masks: bcast15 -> rows 1&3 (0xA),
// bcast31 -> rows 2&3 (0xC).
template<int CTRL, int RMASK>
DEVINL unsigned dpp_addstep(unsigned v) {
    unsigned t = (unsigned)__builtin_amdgcn_update_dpp(0, (int)v, CTRL, RMASK, 0xF, true);
    return v + t;
}
DEVINL unsigned wave_scan_add(unsigned v) {
    v = dpp_addstep<0x111, 0xF>(v);
    v = dpp_addstep<0x112, 0xF>(v);
    v = dpp_addstep<0x114, 0xF>(v);
    v = dpp_addstep<0x118, 0xF>(v);
    v = dpp_addstep<0x142, 0xA>(v);
    v = dpp_addstep<0x143, 0xC>(v);
    return v;
}

// ---------------- shared-memory layouts ----------------
template<int N, int NP> struct __align__(16) FpsS {      // 4-wave FPS
    float4 spts[N];
    int sel[NP];
    u64 rbuf[2][4];
};
struct __align__(16) KnnS {                              // keyless: ~16.4KB -> 8 blk/CU
    unsigned hist[2048];
    unsigned ckey[1024];
    int      cidx[1024];
    unsigned wpart[4];
    unsigned sbin, sKb, scnt, cntL;
};
struct __align__(16) Mlp1S {                             // ~44KB
    float sw1[6*64], sw2[64*64];
    float sb1[64], sb2[64], sb3[128];
    float sx[6*32], sh1[64*36], sh2[64*36];
    float spm[128*4], sout[128*8];
    int   sgi[32];
    float sq[3];
};

// ---------------- weight prep: fp32 transposed (mlp1) + fp16 row-major (mlp2) ------
DEVINL void prep_impl(int e0,
    const float* __restrict__ w10, const float* __restrict__ g10,
    const float* __restrict__ w11, const float* __restrict__ g11,
    const float* __restrict__ w12, const float* __restrict__ g12,
    const float* __restrict__ w20, const float* __restrict__ g20,
    const float* __restrict__ w21, const float* __restrict__ g21,
    const float* __restrict__ w22, const float* __restrict__ g22,
    float* __restrict__ w1t, float* __restrict__ w2t, float* __restrict__ w3t,
    _Float16* __restrict__ W1h, _Float16* __restrict__ W2h, _Float16* __restrict__ W3h)
{
    if (e0 < 384)  { int o = e0/6,   i = e0%6;   w1t [i*64  + o] = w10[e0]*g10[o]; return; }
    e0 -= 384;
    if (e0 < 4096) { int o = e0/64,  i = e0%64;  w2t [i*64  + o] = w11[e0]*g11[o]; return; }
    e0 -= 4096;
    if (e0 < 8192) { int o = e0/64,  i = e0%64;  w3t [i*128 + o] = w12[e0]*g12[o]; return; }
    e0 -= 8192;
    if (e0 < 20480){ int o = e0/160, i = e0%160;
                     float v = (i < 131) ? w20[o*131 + i]*g20[o] : 0.f;
                     W1h[e0] = (_Float16)v; return; }
    e0 -= 20480;
    if (e0 < 16384){ W2h[e0] = (_Float16)(w21[e0]*g21[e0/128]); return; }
    e0 -= 16384;
    if (e0 < 32768){ W3h[e0] = (_Float16)(w22[e0]*g22[e0/128]); return; }
}

// ---------------- FPS 4-wave (R8 structure; exact jnp semantics) ----------------
template<int N, int NP>
DEVINL void fps_impl(FpsS<N, NP>& sm, const float* __restrict__ pts,
                     float* __restrict__ prop, int b, float4* pack_out)
{
    constexpr int NT = 256;
    constexpr int PT = N / NT;
    int tid = threadIdx.x;
    const float* p = pts + (size_t)b * 3 * N;
    for (int n = tid; n < N; n += NT) {
        float x = p[n], y = p[N+n], z = p[2*N+n];
        sm.spts[n] = make_float4(x, y, z, 0.f);
        if (pack_out) {
            float s = __fadd_rn(__fadd_rn(__fmul_rn(x,x), __fmul_rn(y,y)), __fmul_rn(z,z));
            pack_out[(size_t)b*N + n] = make_float4(x, y, z, s);
        }
    }
    __syncthreads();

    float lx[PT], ly[PT], lz[PT], ld[PT];
    int base = tid * PT;
#pragma unroll
    for (int j = 0; j < PT; ++j) {
        float4 q = sm.spts[base+j];
        lx[j] = q.x; ly[j] = q.y; lz[j] = q.z;
        ld[j] = __builtin_inff();
    }
    if (tid == 0) sm.sel[0] = 0;
    float4 qp = sm.spts[0];
    for (int s = 1; s < NP; ++s) {
        float qx = qp.x, qy = qp.y, qz = qp.z;
        float bd = -1.0f; int bi = 0x7FFFFFFF;
#pragma unroll
        for (int j = 0; j < PT; ++j) {
            float dx = __fsub_rn(lx[j], qx);
            float dy = __fsub_rn(ly[j], qy);
            float dz = __fsub_rn(lz[j], qz);
            float dd = __fadd_rn(__fadd_rn(__fmul_rn(dx,dx), __fmul_rn(dy,dy)), __fmul_rn(dz,dz));
            float v = fminf(ld[j], dd);
            ld[j] = v;
            if (v > bd) { bd = v; bi = base + j; }   // ascending j -> lowest idx on tie
        }
        u64 pk = ((u64)__float_as_uint(bd) << 32) | (unsigned)(~bi);
#pragma unroll
        for (int mk = 1; mk < 64; mk <<= 1) {
            u64 o = shflx64(pk, mk);
            if (o > pk) pk = o;
        }
        if ((tid & 63) == 0) sm.rbuf[s & 1][tid >> 6] = pk;
        __syncthreads();
        u64 g = sm.rbuf[s & 1][0];
#pragma unroll
        for (int w = 1; w < 4; ++w) { u64 o = sm.rbuf[s & 1][w]; if (o > g) g = o; }
        int last = (int)(~(unsigned)g);
        qp = sm.spts[last];
        if (tid == 0) sm.sel[s] = last;
    }
    __syncthreads();
    for (int m = tid; m < NP; m += NT) {
        float4 q = sm.spts[sm.sel[m]];
        prop[(size_t)b*3*NP + m]        = q.x;
        prop[(size_t)b*3*NP + NP + m]   = q.y;
        prop[(size_t)b*3*NP + 2*NP + m] = q.z;
    }
}

// ---------------- KNN keyless (packed points): 11-bit histogram select ----------
// Exact K smallest by (dist, idx) lexicographic order; output order arbitrary
// (downstream max-pool is permutation-invariant). 16.4KB LDS -> 8 blocks/CU.
template<int N, int K, int M>
DEVINL void knn_impl(KnnS& sm, const float4* __restrict__ pts4,
                     const float* __restrict__ qry, int* __restrict__ gidx, int bm)
{
    int tid = threadIdx.x, lane = tid & 63, wid = tid >> 6;
    int b = bm / M, m = bm % M;
    const float4* p4 = pts4 + (size_t)b * N;
    float qx = qry[(size_t)b*3*M + m];
    float qy = qry[(size_t)b*3*M + M + m];
    float qz = qry[(size_t)b*3*M + 2*M + m];
    float sqq = __fadd_rn(__fadd_rn(__fmul_rn(qx,qx), __fmul_rn(qy,qy)), __fmul_rn(qz,qz));

    for (int e = tid; e < 2048; e += 256) sm.hist[e] = 0;
    if (tid == 0) { sm.scnt = 0; sm.cntL = 0; sm.sbin = 2047u; sm.sKb = 0; }
    __syncthreads();
    // pass 1: distances from packed points + 11-bit histogram
    for (int n = tid; n < N; n += 256) {
        float4 pp = p4[n];
        float dot = __fadd_rn(__fadd_rn(__fmul_rn(qx,pp.x), __fmul_rn(qy,pp.y)), __fmul_rn(qz,pp.z));
        float d = __fadd_rn(__fsub_rn(sqq, __fmul_rn(2.0f, dot)), pp.w);
        atomicAdd(&sm.hist[fkey(d) >> 21], 1u);
    }
    __syncthreads();
    // locate bin containing the K-th smallest + count strictly before it
    unsigned hloc[8], s8 = 0;
#pragma unroll
    for (int j = 0; j < 8; ++j) { hloc[j] = sm.hist[tid*8 + j]; s8 += hloc[j]; }
    unsigned sc = wave_scan_add(s8);
    if (lane == 63) sm.wpart[wid] = sc;
    __syncthreads();
    unsigned woff = 0;
    for (int w = 0; w < wid; ++w) woff += sm.wpart[w];
    unsigned cumEnd = sc + woff;
    unsigned cbase = cumEnd - s8;
    if ((unsigned)K > cbase && (unsigned)K <= cumEnd) {
        unsigned run = cbase;
#pragma unroll
        for (int j = 0; j < 8; ++j) {
            if ((unsigned)K > run && (unsigned)K <= run + hloc[j]) { sm.sbin = (unsigned)(tid*8 + j); sm.sKb = run; }
            run += hloc[j];
        }
    }
    __syncthreads();
    unsigned bin1 = sm.sbin;
    unsigned Kb   = sm.sKb;     // # keys with prefix < bin1 (all selected)
    int* gout = gidx + ((size_t)b * M + m) * K;
    // pass 2: recompute keys (bit-identical), emit winners, compact boundary bin
    for (int n = tid; n < N; n += 256) {
        float4 pp = p4[n];
        float dot = __fadd_rn(__fadd_rn(__fmul_rn(qx,pp.x), __fmul_rn(qy,pp.y)), __fmul_rn(qz,pp.z));
        float d = __fadd_rn(__fsub_rn(sqq, __fmul_rn(2.0f, dot)), pp.w);
        unsigned k = fkey(d), pfx = k >> 21;
        if (pfx < bin1) {
            unsigned pos = atomicAdd(&sm.cntL, 1u);
            if (pos < (unsigned)K) gout[pos] = n;
        } else if (pfx == bin1) {
            unsigned pos = atomicAdd(&sm.scnt, 1u);
            if (pos < 1024u) { sm.ckey[pos] = k; sm.cidx[pos] = n; }
        }
    }
    __syncthreads();
    int cnt = (int)sm.scnt; if (cnt > 1024) cnt = 1024;
    int need = K - (int)Kb;
    if (tid < 64) {
        for (int c = lane; c < cnt; c += 64) {
            unsigned mk = sm.ckey[c]; int mi = sm.cidx[c];
            int rank = 0;
            for (int l = 0; l < cnt; ++l) {
                unsigned ok = sm.ckey[l];
                rank += (ok < mk || (ok == mk && sm.cidx[l] < mi)) ? 1 : 0;
            }
            if (rank < need && (int)Kb + rank < K) gout[Kb + rank] = mi;
        }
    }
}

// ---------------- layer-1 MLP device impl (sw3 de-staged, ~44KB LDS) ----------------
DEVINL void mlp1_impl(Mlp1S& sm,
    const float* __restrict__ pts,   // [B,3,4096]
    const float* __restrict__ q,     // points1 [B,3,1024]
    const int*   __restrict__ gidx,  // [B,1024,32]
    const float* __restrict__ w1t, const float* __restrict__ w2t, const float* __restrict__ w3t,
    const float* __restrict__ b1, const float* __restrict__ b2, const float* __restrict__ b3,
    float* __restrict__ out, int blk)         // feats1 [B,128,1024]
{
    int tid = threadIdx.x;
    for (int e = tid; e < 6*64;   e += 256) sm.sw1[e] = w1t[e];
    for (int e = tid; e < 64*64;  e += 256) sm.sw2[e] = w2t[e];
    if (tid < 64) { sm.sb1[tid] = b1[tid]; sm.sb2[tid] = b2[tid]; }
    else if (tid < 192) sm.sb3[tid-64] = b3[tid-64];

    int pid0 = blk * 8;
    int b = pid0 >> 10, m0 = pid0 & 1023;
    int c = tid & 63, kq = tid >> 6, kb = kq * 8;
    __syncthreads();

    for (int it = 0; it < 8; ++it) {
        int m = m0 + it;
        if (tid < 32) sm.sgi[tid] = gidx[((size_t)b*1024 + m)*32 + tid];
        else if (tid < 35) sm.sq[tid-32] = q[((size_t)b*3 + (tid-32))*1024 + m];
        __syncthreads();
        if (tid < 192) {
            int cc = tid >> 5, k = tid & 31;
            int gi = sm.sgi[k];
            const float* pb = pts + (size_t)b*3*4096;
            float v = (cc < 3) ? (pb[cc*4096 + gi] - sm.sq[cc]) : pb[(cc-3)*4096 + gi];
            sm.sx[cc*32 + k] = v;
        }
        __syncthreads();
        // L1: 6 -> 64
        float4 a0 = make_float4(0,0,0,0), a1 = make_float4(0,0,0,0);
#pragma unroll
        for (int i = 0; i < 6; ++i) {
            float w = sm.sw1[i*64 + c];
            a0 = f4fma(w, *(const float4*)&sm.sx[i*32 + kb],     a0);
            a1 = f4fma(w, *(const float4*)&sm.sx[i*32 + kb + 4], a1);
        }
        {
            float bias = sm.sb1[c];
            *(float4*)&sm.sh1[c*36 + kb]     = f4relub(a0, bias);
            *(float4*)&sm.sh1[c*36 + kb + 4] = f4relub(a1, bias);
        }
        __syncthreads();
        // L2: 64 -> 64
        a0 = make_float4(0,0,0,0); a1 = make_float4(0,0,0,0);
#pragma unroll 4
        for (int i = 0; i < 64; ++i) {
            float w = sm.sw2[i*64 + c];
            a0 = f4fma(w, *(const float4*)&sm.sh1[i*36 + kb],     a0);
            a1 = f4fma(w, *(const float4*)&sm.sh1[i*36 + kb + 4], a1);
        }
        {
            float bias = sm.sb2[c];
            *(float4*)&sm.sh2[c*36 + kb]     = f4relub(a0, bias);
            *(float4*)&sm.sh2[c*36 + kb + 4] = f4relub(a1, bias);
        }
        __syncthreads();
        // L3: 64 -> 128 (2 channels/thread), weights straight from L2
        float4 aA0 = make_float4(0,0,0,0), aA1 = make_float4(0,0,0,0);
        float4 aB0 = make_float4(0,0,0,0), aB1 = make_float4(0,0,0,0);
#pragma unroll 4
        for (int i = 0; i < 64; ++i) {
            float wA = w3t[i*128 + c], wB = w3t[i*128 + c + 64];
            float4 v0 = *(const float4*)&sm.sh2[i*36 + kb];
            float4 v1 = *(const float4*)&sm.sh2[i*36 + kb + 4];
            aA0 = f4fma(wA, v0, aA0); aA1 = f4fma(wA, v1, aA1);
            aB0 = f4fma(wB, v0, aB0); aB1 = f4fma(wB, v1, aB1);
        }
        float mA = fmaxf(fmaxf(f4max(aA0), f4max(aA1)) + sm.sb3[c],      0.f);
        float mB = fmaxf(fmaxf(f4max(aB0), f4max(aB1)) + sm.sb3[c + 64], 0.f);
        sm.spm[c*4 + kq]        = mA;
        sm.spm[(c + 64)*4 + kq] = mB;
        __syncthreads();
        if (tid < 128) {
            float f = fmaxf(fmaxf(sm.spm[tid*4], sm.spm[tid*4+1]), fmaxf(sm.spm[tid*4+2], sm.spm[tid*4+3]));
            sm.sout[tid*8 + it] = f;
        }
        __syncthreads();
    }
    for (int e = tid; e < 128*8; e += 256) {
        int cc = e >> 3, j = e & 7;
        out[((size_t)b*128 + cc)*1024 + m0 + j] = sm.sout[e];
    }
}

// ---------------- fused kernels ----------------
// K1: fps1 (0..15) || prep (16..337) || pack pts4 (338..401)
__global__ __launch_bounds__(256) void fused1(
    const float* __restrict__ pts, float* __restrict__ p1, float4* __restrict__ pts4,
    const float* w10, const float* g10, const float* w11, const float* g11,
    const float* w12, const float* g12, const float* w20, const float* g20,
    const float* w21, const float* g21, const float* w22, const float* g22,
    float* w1t, float* w2t, float* w3t,
    _Float16* W1h, _Float16* W2h, _Float16* W3h)
{
    __shared__ FpsS<4096, 1024> sm;
    if (blockIdx.x < 16) {
        fps_impl<4096, 1024>(sm, pts, p1, blockIdx.x, nullptr);
    } else if (blockIdx.x < 338) {
        prep_impl((blockIdx.x - 16) * 256 + threadIdx.x,
                  w10, g10, w11, g11, w12, g12, w20, g20, w21, g21, w22, g22,
                  w1t, w2t, w3t, W1h, W2h, W3h);
    } else {
        int pblk = blockIdx.x - 338;   // 0..63, 1024 points each
#pragma unroll
        for (int i = 0; i < 4; ++i) {
            int idx = pblk * 1024 + i * 256 + threadIdx.x;
            int b = idx >> 12, n = idx & 4095;
            const float* p = pts + (size_t)b * 3 * 4096;
            float x = p[n], y = p[4096 + n], z = p[2*4096 + n];
            float s = __fadd_rn(__fadd_rn(__fmul_rn(x,x), __fmul_rn(y,y)), __fmul_rn(z,z));
            pts4[idx] = make_float4(x, y, z, s);
        }
    }
}

// K2: fps2 4-wave (0..15, packs p14) || knn1 (16..16399)
union SmemK2 { FpsS<1024, 256> fps; KnnS knn; };
__global__ __launch_bounds__(256) void fused2(
    const float4* __restrict__ pts4, const float* __restrict__ p1,
    float* __restrict__ p2, int* __restrict__ gidx1, float4* __restrict__ p14)
{
    __shared__ SmemK2 sm;
    if (blockIdx.x < 16) {
        fps_impl<1024, 256>(sm.fps, p1, p2, blockIdx.x, p14);
    } else {
        knn_impl<4096, 32, 1024>(sm.knn, pts4, p1, gidx1, blockIdx.x - 16);
    }
}

// K3: mlp1 (0..2047) || knn2 (2048..6143)
union SmemK3 { Mlp1S mlp; KnnS knn; };
__global__ __launch_bounds__(256) void fused3(
    const float* __restrict__ pts, const float* __restrict__ p1,
    const int* __restrict__ gidx1,
    const float* __restrict__ w1t, const float* __restrict__ w2t, const float* __restrict__ w3t,
    const float* __restrict__ b1, const float* __restrict__ b2, const float* __restrict__ b3,
    float* __restrict__ f1,
    const float4* __restrict__ p14, const float* __restrict__ p2, int* __restrict__ gidx2)
{
    __shared__ SmemK3 sm;
    if (blockIdx.x < 2048) {
        mlp1_impl(sm.mlp, pts, p1, gidx1, w1t, w2t, w3t, b1, b2, b3, f1, blockIdx.x);
    } else {
        knn_impl<1024, 64, 256>(sm.knn, p14, p2, gidx2, blockIdx.x - 2048);
    }
}

// ---------------- K4: mlp2 via fp16 MFMA ----------------
// One block per (b,m): gather X[131][64] -> fp16 xT[64][160(pad168)], then
// 3 GEMMs on matrix cores (fp32 accum), bias+relu in fp32, h requantized fp16.
// Fragment layouts: A row=l&15, k=8*(l>>4)+j (8 contiguous K); B col=l&15 same
// k-chunk; C/D col=l&15, row=4*(l>>4)+reg (m89-verified).
__global__ __launch_bounds__(256) void mlp2_kernel(
    const float* __restrict__ p1,   // [B,3,1024]
    const float* __restrict__ f1,   // [B,128,1024]
    const float* __restrict__ q2,   // [B,3,256]
    const int*   __restrict__ gidx, // [B,256,64]
    const _Float16* __restrict__ W1h,  // [128][160]
    const _Float16* __restrict__ W2h,  // [128][128]
    const _Float16* __restrict__ W3h,  // [256][128]
    const float* __restrict__ b20, const float* __restrict__ b21, const float* __restrict__ b22,
    float* __restrict__ out)        // feats2 [B,256,256]
{
    __shared__ _Float16 xT[64*168];    // X^T (n-major, stride 168); later h2T (stride 136)
    __shared__ _Float16 h1T[64*136];
    __shared__ int   sgi[64];
    __shared__ float sq[3];

    int tid = threadIdx.x;
    int b = blockIdx.x >> 8, m = blockIdx.x & 255;
    if (tid < 64) sgi[tid] = gidx[((size_t)b*256 + m)*64 + tid];
    else if (tid < 67) sq[tid-64] = q2[((size_t)b*3 + (tid-64))*256 + m];
    __syncthreads();

    // gather + quantize + zero-pad (K 131 -> 160), packed 4 halves per write
    union Pk4 { _Float16 h[4]; u64 u; };
    for (int e = tid; e < 40*64; e += 256) {
        int qi = e >> 6, n = e & 63;
        int gi = sgi[n];
        Pk4 pk;
#pragma unroll
        for (int j = 0; j < 4; ++j) {
            int i = qi*4 + j;
            float v;
            if (i < 3)        v = p1[((size_t)b*3 + i)*1024 + gi] - sq[i];
            else if (i < 131) v = f1[((size_t)b*128 + (i-3))*1024 + gi];
            else              v = 0.f;
            pk.h[j] = (_Float16)v;
        }
        *(u64*)&xT[n*168 + qi*4] = pk.u;
    }
    __syncthreads();

    int wv = tid >> 6, l = tid & 63;
    int lr = l & 15, lk = l >> 4;

    // ---- GEMM1: Y1[128][64] = W1[128][160] * X[160][64] ----
    f32x4 acc[2][4];
#pragma unroll
    for (int mi = 0; mi < 2; ++mi)
#pragma unroll
        for (int nt = 0; nt < 4; ++nt) acc[mi][nt] = (f32x4){0.f,0.f,0.f,0.f};
#pragma unroll
    for (int ks = 0; ks < 5; ++ks) {
        int kk = ks*32 + lk*8;
        f16x8 bf[4];
#pragma unroll
        for (int nt = 0; nt < 4; ++nt)
            bf[nt] = *(const f16x8*)&xT[(nt*16 + lr)*168 + kk];
#pragma unroll
        for (int mi = 0; mi < 2; ++mi) {
            f16x8 af = *(const f16x8*)&W1h[(size_t)((wv*2 + mi)*16 + lr)*160 + kk];
#pragma unroll
            for (int nt = 0; nt < 4; ++nt)
                acc[mi][nt] = __builtin_amdgcn_mfma_f32_16x16x32_f16(af, bf[nt], acc[mi][nt], 0, 0, 0);
        }
    }
    // epilogue: h1 = relu(y + b20), fp16 -> h1T[n][ch] (4 consecutive ch per write)
#pragma unroll
    for (int mi = 0; mi < 2; ++mi) {
        int ch0 = (wv*2 + mi)*16 + lk*4;
        float bb0 = b20[ch0], bb1 = b20[ch0+1], bb2 = b20[ch0+2], bb3 = b20[ch0+3];
#pragma unroll
        for (int nt = 0; nt < 4; ++nt) {
            int n = nt*16 + lr;
            Pk4 pk;
            pk.h[0] = (_Float16)fmaxf(acc[mi][nt][0] + bb0, 0.f);
            pk.h[1] = (_Float16)fmaxf(acc[mi][nt][1] + bb1, 0.f);
            pk.h[2] = (_Float16)fmaxf(acc[mi][nt][2] + bb2, 0.f);
            pk.h[3] = (_Float16)fmaxf(acc[mi][nt][3] + bb3, 0.f);
            *(u64*)&h1T[n*136 + ch0] = pk.u;
        }
    }
    __syncthreads();

    // ---- GEMM2: Y2[128][64] = W2[128][128] * H1[128][64]; h2T into xT region ----
    _Float16* h2T = xT;   // stride 136 reuse (X is dead; all reads fenced above)
#pragma unroll
    for (int mi = 0; mi < 2; ++mi)
#pragma unroll
        for (int nt = 0; nt < 4; ++nt) acc[mi][nt] = (f32x4){0.f,0.f,0.f,0.f};
#pragma unroll
    for (int ks = 0; ks < 4; ++ks) {
        int kk = ks*32 + lk*8;
        f16x8 bf[4];
#pragma unroll
        for (int nt = 0; nt < 4; ++nt)
            bf[nt] = *(const f16x8*)&h1T[(nt*16 + lr)*136 + kk];
#pragma unroll
        for (int mi = 0; mi < 2; ++mi) {
            f16x8 af = *(const f16x8*)&W2h[(size_t)((wv*2 + mi)*16 + lr)*128 + kk];
#pragma unroll
            for (int nt = 0; nt < 4; ++nt)
                acc[mi][nt] = __builtin_amdgcn_mfma_f32_16x16x32_f16(af, bf[nt], acc[mi][nt], 0, 0, 0);
        }
    }
    __syncthreads();   // all GEMM2 h1T reads done before h2T (xT region) writes? h2T != h1T, but ensure X-region reads... X dead; keep barrier for h2T-write vs any straggler ordering
#pragma unroll
    for (int mi = 0; mi < 2; ++mi) {
        int ch0 = (wv*2 + mi)*16 + lk*4;
        float bb0 = b21[ch0], bb1 = b21[ch0+1], bb2 = b21[ch0+2], bb3 = b21[ch0+3];
#pragma unroll
        for (int nt = 0; nt < 4; ++nt) {
            int n = nt*16 + lr;
            Pk4 pk;
            pk.h[0] = (_Float16)fmaxf(acc[mi][nt][0] + bb0, 0.f);
            pk.h[1] = (_Float16)fmaxf(acc[mi][nt][1] + bb1, 0.f);
            pk.h[2] = (_Float16)fmaxf(acc[mi][nt][2] + bb2, 0.f);
            pk.h[3] = (_Float16)fmaxf(acc[mi][nt][3] + bb3, 0.f);
            *(u64*)&h2T[n*136 + ch0] = pk.u;
        }
    }
    __syncthreads();

    // ---- GEMM3: Y3[256][64] = W3[256][128] * H2[128][64], maxpool over n ----
    f32x4 acc3[4][4];
#pragma unroll
    for (int mi = 0; mi < 4; ++mi)
#pragma unroll
        for (int nt = 0; nt < 4; ++nt) acc3[mi][nt] = (f32x4){0.f,0.f,0.f,0.f};
#pragma unroll
    for (int ks = 0; ks < 4; ++ks) {
        int kk = ks*32 + lk*8;
        f16x8 bf[4];
#pragma unroll
        for (int nt = 0; nt < 4; ++nt)
            bf[nt] = *(const f16x8*)&h2T[(nt*16 + lr)*136 + kk];
#pragma unroll
        for (int mi = 0; mi < 4; ++mi) {
            f16x8 af = *(const f16x8*)&W3h[(size_t)((wv*4 + mi)*16 + lr)*128 + kk];
#pragma unroll
            for (int nt = 0; nt < 4; ++nt)
                acc3[mi][nt] = __builtin_amdgcn_mfma_f32_16x16x32_f16(af, bf[nt], acc3[mi][nt], 0, 0, 0);
        }
    }
    // maxpool over 64 n: per-lane max over 4 ntiles, then shfl_xor over 16-col group
#pragma unroll
    for (int mi = 0; mi < 4; ++mi) {
        float v0 = acc3[mi][0][0], v1 = acc3[mi][0][1], v2 = acc3[mi][0][2], v3 = acc3[mi][0][3];
#pragma unroll
        for (int nt = 1; nt < 4; ++nt) {
            v0 = fmaxf(v0, acc3[mi][nt][0]);
            v1 = fmaxf(v1, acc3[mi][nt][1]);
            v2 = fmaxf(v2, acc3[mi][nt][2]);
            v3 = fmaxf(v3, acc3[mi][nt][3]);
        }
#pragma unroll
        for (int mk = 1; mk < 16; mk <<= 1) {
            v0 = fmaxf(v0, __shfl_xor(v0, mk));
            v1 = fmaxf(v1, __shfl_xor(v1, mk));
            v2 = fmaxf(v2, __shfl_xor(v2, mk));
            v3 = fmaxf(v3, __shfl_xor(v3, mk));
        }
        if (lr == 0) {
            int ch0 = (wv*4 + mi)*16 + lk*4;
            out[((size_t)b*256 + ch0    )*256 + m] = fmaxf(v0 + b22[ch0],     0.f);
            out[((size_t)b*256 + ch0 + 1)*256 + m] = fmaxf(v1 + b22[ch0 + 1], 0.f);
            out[((size_t)b*256 + ch0 + 2)*256 + m] = fmaxf(v2 + b22[ch0 + 2], 0.f);
            out[((size_t)b*256 + ch0 + 3)*256 + m] = fmaxf(v3 + b22[ch0 + 3], 0.f);
        }
    }
}

// ---------------- launch ----------------
extern "C" void kernel_launch(void* const* d_in, const int* in_sizes, int n_in,
                              void* d_out, int out_size, void* d_ws, size_t ws_size,
                              hipStream_t stream)
{
    const float* pts = (const float*)d_in[0];
    const float* w10 = (const float*)d_in[1];
    const float* g10 = (const float*)d_in[2];
    const float* b10 = (const float*)d_in[3];
    const float* w11 = (const float*)d_in[4];
    const float* g11 = (const float*)d_in[5];
    const float* b11 = (const float*)d_in[6];
    const float* w12 = (const float*)d_in[7];
    const float* g12 = (const float*)d_in[8];
    const float* b12 = (const float*)d_in[9];
    const float* w20 = (const float*)d_in[10];
    const float* g20 = (const float*)d_in[11];
    const float* b20 = (const float*)d_in[12];
    const float* w21 = (const float*)d_in[13];
    const float* g21 = (const float*)d_in[14];
    const float* b21 = (const float*)d_in[15];
    const float* w22 = (const float*)d_in[16];
    const float* g22 = (const float*)d_in[17];
    const float* b22 = (const float*)d_in[18];

    float* out = (float*)d_out;
    char* ws = (char*)d_ws;
    int* gidx1 = (int*)(ws + WS_GIDX1);
    int* gidx2 = (int*)(ws + WS_GIDX2);
    float* w1t  = (float*)(ws + WS_W1T);
    float* w2t  = (float*)(ws + WS_W2T);
    float* w3t  = (float*)(ws + WS_W3T);
    _Float16* W1h = (_Float16*)(ws + WS_W1H);
    _Float16* W2h = (_Float16*)(ws + WS_W2H);
    _Float16* W3h = (_Float16*)(ws + WS_W3H);
    float4* pts4 = (float4*)(ws + WS_PTS4);
    float4* p14  = (float4*)(ws + WS_P14);

    float* p1 = out + O_P1;   // [16,3,1024]
    float* f1 = out + O_F1;   // [16,128,1024]
    float* p2 = out + O_P2;   // [16,3,256]
    float* f2 = out + O_F2;   // [16,256,256]

    // K1: fps1 || prep (fp32 + fp16 weights) || pack pts4
    fused1<<<16 + 322 + 64, 256, 0, stream>>>(pts, p1, pts4,
                                              w10, g10, w11, g11, w12, g12,
                                              w20, g20, w21, g21, w22, g22,
                                              w1t, w2t, w3t, W1h, W2h, W3h);
    // K2: fps2 (packs p14) || knn1
    fused2<<<16 + NB * 1024, 256, 0, stream>>>(pts4, p1, p2, gidx1, p14);
    // K3: mlp1 || knn2
    fused3<<<2048 + NB * 256, 256, 0, stream>>>(pts, p1, gidx1,
                                                w1t, w2t, w3t, b10, b11, b12, f1,
                                                p14, p2, gidx2);
    // K4: mlp2 (fp16 MFMA)
    mlp2_kernel<<<NB * 256, 256, 0, stream>>>(p1, f1, p2, gidx2,
                                              W1h, W2h, W3h, b20, b21, b22, f2);
}

// Round 15
// 1123.187 us; speedup vs baseline: 1.4069x; 1.1180x over previous
//
#include <hip/hip_runtime.h>
#include <math.h>

// ---------------- problem constants ----------------
#define NB   16

// d_out float offsets
#define O_P1 0
#define O_F1 (16*3*1024)            // 49152
#define O_P2 (O_F1 + 16*128*1024)   // 2146304
#define O_F2 (O_P2 + 16*3*256)      // 2158592

// workspace byte offsets
#define WS_GIDX1 0
#define WS_GIDX2 (WS_GIDX1 + 16*1024*32*4)
#define WS_W1H   (WS_GIDX2 + 16*256*64*4)     // fp16 [128][160]  (mlp2 L1)
#define WS_W2H   (WS_W1H  + 128*160*2)        // fp16 [128][128]
#define WS_W3H   (WS_W2H  + 128*128*2)        // fp16 [256][128]
#define WS_W1MH  (WS_W3H  + 256*128*2)        // fp16 [64][32]    (mlp1 L1, K pad 32)
#define WS_W2MH  (WS_W1MH + 64*32*2)          // fp16 [64][64]
#define WS_W3MH  (WS_W2MH + 64*64*2)          // fp16 [128][64]
#define WS_PTS4  (WS_W3MH + 128*64*2)         // float4[16][4096] (x,y,z,|p|^2)
#define WS_P14   (WS_PTS4 + 16*4096*16)       // float4[16][1024] packed p1

#define DEVINL __device__ __forceinline__
typedef unsigned long long u64;
typedef _Float16 f16x8 __attribute__((ext_vector_type(8)));
typedef float f32x4 __attribute__((ext_vector_type(4)));

// order-preserving float -> uint mapping (monotone increasing)
DEVINL unsigned fkey(float f) {
    unsigned u = __float_as_uint(f);
    return (u & 0x80000000u) ? ~u : (u | 0x80000000u);
}

DEVINL u64 shflx64(u64 v, int m) {
    unsigned lo = __shfl_xor((unsigned)v, m);
    unsigned hi = __shfl_xor((unsigned)(v >> 32), m);
    return ((u64)hi << 32) | lo;
}

// inclusive add-scan within wave64 (bcast15 -> rows 1&3, bcast31 -> rows 2&3)
template<int CTRL, int RMASK>
DEVINL unsigned dpp_addstep(unsigned v) {
    unsigned t = (unsigned)__builtin_amdgcn_update_dpp(0, (int)v, CTRL, RMASK, 0xF, true);
    return v + t;
}
DEVINL unsigned wave_scan_add(unsigned v) {
    v = dpp_addstep<0x111, 0xF>(v);
    v = dpp_addstep<0x112, 0xF>(v);
    v = dpp_addstep<0x114, 0xF>(v);
    v = dpp_addstep<0x118, 0xF>(v);
    v = dpp_addstep<0x142, 0xA>(v);
    v = dpp_addstep<0x143, 0xC>(v);
    return v;
}

// XOR-swizzled half-index helpers (16B chunks) — SAME function for write & read.
DEVINL int swz32(int n, int h) {   // row stride 32 halves (64B), 4 chunks
    return n*32 + (((h >> 3) ^ (n & 3)) << 3) + (h & 7);
}
DEVINL int swz64(int n, int h) {   // row stride 64 halves (128B), 8 chunks
    return n*64 + (((h >> 3) ^ (n & 7)) << 3) + (h & 7);
}

// ---------------- shared-memory layouts ----------------
template<int N, int NP> struct __align__(16) FpsS {      // 4-wave FPS
    float4 spts[N];
    int sel[NP];
    u64 rbuf[2][4];
};
struct __align__(16) KnnS {                              // keyless: ~16.4KB -> 8 blk/CU
    unsigned hist[2048];
    unsigned ckey[1024];
    int      cidx[1024];
    unsigned wpart[4];
    unsigned sbin, sKb, scnt, cntL;
};

// ---------------- weight prep: all fp16, gamma-folded ----------------
DEVINL void prep_impl(int e0,
    const float* __restrict__ w10, const float* __restrict__ g10,
    const float* __restrict__ w11, const float* __restrict__ g11,
    const float* __restrict__ w12, const float* __restrict__ g12,
    const float* __restrict__ w20, const float* __restrict__ g20,
    const float* __restrict__ w21, const float* __restrict__ g21,
    const float* __restrict__ w22, const float* __restrict__ g22,
    _Float16* __restrict__ W1h, _Float16* __restrict__ W2h, _Float16* __restrict__ W3h,
    _Float16* __restrict__ W1mh, _Float16* __restrict__ W2mh, _Float16* __restrict__ W3mh)
{
    if (e0 < 20480){ int o = e0/160, i = e0%160;
                     float v = (i < 131) ? w20[o*131 + i]*g20[o] : 0.f;
                     W1h[e0] = (_Float16)v; return; }
    e0 -= 20480;
    if (e0 < 16384){ W2h[e0] = (_Float16)(w21[e0]*g21[e0/128]); return; }
    e0 -= 16384;
    if (e0 < 32768){ W3h[e0] = (_Float16)(w22[e0]*g22[e0/128]); return; }
    e0 -= 32768;
    if (e0 < 2048) { int o = e0>>5, i = e0&31;
                     float v = (i < 6) ? w10[o*6 + i]*g10[o] : 0.f;
                     W1mh[e0] = (_Float16)v; return; }
    e0 -= 2048;
    if (e0 < 4096) { W2mh[e0] = (_Float16)(w11[e0]*g11[e0>>6]); return; }
    e0 -= 4096;
    if (e0 < 8192) { W3mh[e0] = (_Float16)(w12[e0]*g12[e0>>6]); return; }
}

// ---------------- FPS 4-wave (R8 structure; exact jnp semantics) ----------------
template<int N, int NP>
DEVINL void fps_impl(FpsS<N, NP>& sm, const float* __restrict__ pts,
                     float* __restrict__ prop, int b, float4* pack_out)
{
    constexpr int NT = 256;
    constexpr int PT = N / NT;
    int tid = threadIdx.x;
    const float* p = pts + (size_t)b * 3 * N;
    for (int n = tid; n < N; n += NT) {
        float x = p[n], y = p[N+n], z = p[2*N+n];
        sm.spts[n] = make_float4(x, y, z, 0.f);
        if (pack_out) {
            float s = __fadd_rn(__fadd_rn(__fmul_rn(x,x), __fmul_rn(y,y)), __fmul_rn(z,z));
            pack_out[(size_t)b*N + n] = make_float4(x, y, z, s);
        }
    }
    __syncthreads();

    float lx[PT], ly[PT], lz[PT], ld[PT];
    int base = tid * PT;
#pragma unroll
    for (int j = 0; j < PT; ++j) {
        float4 q = sm.spts[base+j];
        lx[j] = q.x; ly[j] = q.y; lz[j] = q.z;
        ld[j] = __builtin_inff();
    }
    if (tid == 0) sm.sel[0] = 0;
    float4 qp = sm.spts[0];
    for (int s = 1; s < NP; ++s) {
        float qx = qp.x, qy = qp.y, qz = qp.z;
        float bd = -1.0f; int bi = 0x7FFFFFFF;
#pragma unroll
        for (int j = 0; j < PT; ++j) {
            float dx = __fsub_rn(lx[j], qx);
            float dy = __fsub_rn(ly[j], qy);
            float dz = __fsub_rn(lz[j], qz);
            float dd = __fadd_rn(__fadd_rn(__fmul_rn(dx,dx), __fmul_rn(dy,dy)), __fmul_rn(dz,dz));
            float v = fminf(ld[j], dd);
            ld[j] = v;
            if (v > bd) { bd = v; bi = base + j; }   // ascending j -> lowest idx on tie
        }
        u64 pk = ((u64)__float_as_uint(bd) << 32) | (unsigned)(~bi);
#pragma unroll
        for (int mk = 1; mk < 64; mk <<= 1) {
            u64 o = shflx64(pk, mk);
            if (o > pk) pk = o;
        }
        if ((tid & 63) == 0) sm.rbuf[s & 1][tid >> 6] = pk;
        __syncthreads();
        u64 g = sm.rbuf[s & 1][0];
#pragma unroll
        for (int w = 1; w < 4; ++w) { u64 o = sm.rbuf[s & 1][w]; if (o > g) g = o; }
        int last = (int)(~(unsigned)g);
        qp = sm.spts[last];
        if (tid == 0) sm.sel[s] = last;
    }
    __syncthreads();
    for (int m = tid; m < NP; m += NT) {
        float4 q = sm.spts[sm.sel[m]];
        prop[(size_t)b*3*NP + m]        = q.x;
        prop[(size_t)b*3*NP + NP + m]   = q.y;
        prop[(size_t)b*3*NP + 2*NP + m] = q.z;
    }
}

// ---------------- KNN keyless (packed points): 11-bit histogram select ----------
template<int N, int K, int M>
DEVINL void knn_impl(KnnS& sm, const float4* __restrict__ pts4,
                     const float* __restrict__ qry, int* __restrict__ gidx, int bm)
{
    int tid = threadIdx.x, lane = tid & 63, wid = tid >> 6;
    int b = bm / M, m = bm % M;
    const float4* p4 = pts4 + (size_t)b * N;
    float qx = qry[(size_t)b*3*M + m];
    float qy = qry[(size_t)b*3*M + M + m];
    float qz = qry[(size_t)b*3*M + 2*M + m];
    float sqq = __fadd_rn(__fadd_rn(__fmul_rn(qx,qx), __fmul_rn(qy,qy)), __fmul_rn(qz,qz));

    for (int e = tid; e < 2048; e += 256) sm.hist[e] = 0;
    if (tid == 0) { sm.scnt = 0; sm.cntL = 0; sm.sbin = 2047u; sm.sKb = 0; }
    __syncthreads();
    for (int n = tid; n < N; n += 256) {
        float4 pp = p4[n];
        float dot = __fadd_rn(__fadd_rn(__fmul_rn(qx,pp.x), __fmul_rn(qy,pp.y)), __fmul_rn(qz,pp.z));
        float d = __fadd_rn(__fsub_rn(sqq, __fmul_rn(2.0f, dot)), pp.w);
        atomicAdd(&sm.hist[fkey(d) >> 21], 1u);
    }
    __syncthreads();
    unsigned hloc[8], s8 = 0;
#pragma unroll
    for (int j = 0; j < 8; ++j) { hloc[j] = sm.hist[tid*8 + j]; s8 += hloc[j]; }
    unsigned sc = wave_scan_add(s8);
    if (lane == 63) sm.wpart[wid] = sc;
    __syncthreads();
    unsigned woff = 0;
    for (int w = 0; w < wid; ++w) woff += sm.wpart[w];
    unsigned cumEnd = sc + woff;
    unsigned cbase = cumEnd - s8;
    if ((unsigned)K > cbase && (unsigned)K <= cumEnd) {
        unsigned run = cbase;
#pragma unroll
        for (int j = 0; j < 8; ++j) {
            if ((unsigned)K > run && (unsigned)K <= run + hloc[j]) { sm.sbin = (unsigned)(tid*8 + j); sm.sKb = run; }
            run += hloc[j];
        }
    }
    __syncthreads();
    unsigned bin1 = sm.sbin;
    unsigned Kb   = sm.sKb;
    int* gout = gidx + ((size_t)b * M + m) * K;
    for (int n = tid; n < N; n += 256) {
        float4 pp = p4[n];
        float dot = __fadd_rn(__fadd_rn(__fmul_rn(qx,pp.x), __fmul_rn(qy,pp.y)), __fmul_rn(qz,pp.z));
        float d = __fadd_rn(__fsub_rn(sqq, __fmul_rn(2.0f, dot)), pp.w);
        unsigned k = fkey(d), pfx = k >> 21;
        if (pfx < bin1) {
            unsigned pos = atomicAdd(&sm.cntL, 1u);
            if (pos < (unsigned)K) gout[pos] = n;
        } else if (pfx == bin1) {
            unsigned pos = atomicAdd(&sm.scnt, 1u);
            if (pos < 1024u) { sm.ckey[pos] = k; sm.cidx[pos] = n; }
        }
    }
    __syncthreads();
    int cnt = (int)sm.scnt; if (cnt > 1024) cnt = 1024;
    int need = K - (int)Kb;
    if (tid < 64) {
        for (int c = lane; c < cnt; c += 64) {
            unsigned mk = sm.ckey[c]; int mi = sm.cidx[c];
            int rank = 0;
            for (int l = 0; l < cnt; ++l) {
                unsigned ok = sm.ckey[l];
                rank += (ok < mk || (ok == mk && sm.cidx[l] < mi)) ? 1 : 0;
            }
            if (rank < need && (int)Kb + rank < K) gout[Kb + rank] = mi;
        }
    }
}

// ---------------- fused kernels ----------------
// K1: fps1 (0..15) || prep fp16 weights (16..343) || pack pts4 (344..407)
__global__ __launch_bounds__(256) void fused1(
    const float* __restrict__ pts, float* __restrict__ p1, float4* __restrict__ pts4,
    const float* w10, const float* g10, const float* w11, const float* g11,
    const float* w12, const float* g12, const float* w20, const float* g20,
    const float* w21, const float* g21, const float* w22, const float* g22,
    _Float16* W1h, _Float16* W2h, _Float16* W3h,
    _Float16* W1mh, _Float16* W2mh, _Float16* W3mh)
{
    __shared__ FpsS<4096, 1024> sm;
    if (blockIdx.x < 16) {
        fps_impl<4096, 1024>(sm, pts, p1, blockIdx.x, nullptr);
    } else if (blockIdx.x < 344) {
        prep_impl((blockIdx.x - 16) * 256 + threadIdx.x,
                  w10, g10, w11, g11, w12, g12, w20, g20, w21, g21, w22, g22,
                  W1h, W2h, W3h, W1mh, W2mh, W3mh);
    } else {
        int pblk = blockIdx.x - 344;   // 0..63, 1024 points each
#pragma unroll
        for (int i = 0; i < 4; ++i) {
            int idx = pblk * 1024 + i * 256 + threadIdx.x;
            int b = idx >> 12, n = idx & 4095;
            const float* p = pts + (size_t)b * 3 * 4096;
            float x = p[n], y = p[4096 + n], z = p[2*4096 + n];
            float s = __fadd_rn(__fadd_rn(__fmul_rn(x,x), __fmul_rn(y,y)), __fmul_rn(z,z));
            pts4[idx] = make_float4(x, y, z, s);
        }
    }
}

// K2: fps2 4-wave (0..15, packs p14) || knn1 (16..16399)
union SmemK2 { FpsS<1024, 256> fps; KnnS knn; };
__global__ __launch_bounds__(256) void fused2(
    const float4* __restrict__ pts4, const float* __restrict__ p1,
    float* __restrict__ p2, int* __restrict__ gidx1, float4* __restrict__ p14)
{
    __shared__ SmemK2 sm;
    if (blockIdx.x < 16) {
        fps_impl<1024, 256>(sm.fps, p1, p2, blockIdx.x, p14);
    } else {
        knn_impl<4096, 32, 1024>(sm.knn, pts4, p1, gidx1, blockIdx.x - 16);
    }
}

// ---------------- K3: mlp1 via fp16 MFMA ----------------
// One block per 8 positions: gather 256 neighbor-columns -> fp16 xT (K=6 pad 32,
// XOR-swizzled), 3 GEMMs (64x32x256, 64x64x256, 128x64x256). Each wave owns 4
// N-tiles (= 2 positions) and all out-channels -> h rows are wave-local: no
// barriers in the GEMM chain. Maxpool over 32-sample groups, fp32 epilogues.
__global__ __launch_bounds__(256) void mlp1_mfma(
    const float4* __restrict__ pts4,  // [B][4096] packed
    const float* __restrict__ q,      // points1 [B,3,1024]
    const int*   __restrict__ gidx,   // [B,1024,32]
    const _Float16* __restrict__ W1mh, // [64][32]
    const _Float16* __restrict__ W2mh, // [64][64]
    const _Float16* __restrict__ W3mh, // [128][64]
    const float* __restrict__ b1, const float* __restrict__ b2, const float* __restrict__ b3,
    float* __restrict__ out)          // feats1 [B,128,1024]
{
    __shared__ _Float16 xT [256*32];   // swizzled, stride 32
    __shared__ _Float16 h1T[256*64];   // swizzled, stride 64 (h1 -> h2 in place)
    __shared__ float sout[128*8];
    __shared__ int   sgi[256];
    __shared__ float sq[24];           // [c][pos]

    int tid = threadIdx.x;
    int pid0 = blockIdx.x * 8;
    int b = pid0 >> 10, m0 = pid0 & 1023;

    sgi[tid] = gidx[((size_t)b*1024 + m0)*32 + tid];
    if (tid < 24) {
        int c = tid >> 3, j = tid & 7;
        sq[tid] = q[((size_t)b*3 + c)*1024 + m0 + j];
    }
    __syncthreads();

    // gather: thread = column n; x = [p-q (3), p (3), 0...]; fp16, swizzled writes
    union Pk4 { _Float16 h[4]; u64 u; };
    {
        int n = tid, pos = n >> 5;
        float4 pp = pts4[(size_t)b*4096 + sgi[n]];
        float v[8];
        v[0] = pp.x - sq[pos]; v[1] = pp.y - sq[8+pos]; v[2] = pp.z - sq[16+pos];
        v[3] = pp.x; v[4] = pp.y; v[5] = pp.z; v[6] = 0.f; v[7] = 0.f;
#pragma unroll
        for (int qi = 0; qi < 8; ++qi) {
            Pk4 pk;
            if (qi < 2) {
#pragma unroll
                for (int j = 0; j < 4; ++j) pk.h[j] = (_Float16)v[qi*4 + j];
            } else pk.u = 0;
            *(u64*)&xT[swz32(n, qi*4)] = pk.u;
        }
    }
    __syncthreads();

    int wv = tid >> 6, l = tid & 63;
    int lr = l & 15, lk = l >> 4;

    // ---- GEMM1: H1[64][256] = W1[64][32] * X[32][256] (1 k-step) ----
    f32x4 acc[4][4];
#pragma unroll
    for (int mi = 0; mi < 4; ++mi)
#pragma unroll
        for (int nt = 0; nt < 4; ++nt) acc[mi][nt] = (f32x4){0.f,0.f,0.f,0.f};
    {
        int kk = lk*8;
        f16x8 bf[4];
#pragma unroll
        for (int nt = 0; nt < 4; ++nt)
            bf[nt] = *(const f16x8*)&xT[swz32((4*wv + nt)*16 + lr, kk)];
#pragma unroll
        for (int mi = 0; mi < 4; ++mi) {
            f16x8 af = *(const f16x8*)&W1mh[(mi*16 + lr)*32 + kk];
#pragma unroll
            for (int nt = 0; nt < 4; ++nt)
                acc[mi][nt] = __builtin_amdgcn_mfma_f32_16x16x32_f16(af, bf[nt], acc[mi][nt], 0, 0, 0);
        }
    }
    // epilogue -> h1T (wave-local rows)
#pragma unroll
    for (int mi = 0; mi < 4; ++mi) {
        int ch0 = mi*16 + lk*4;
        float bb0 = b1[ch0], bb1 = b1[ch0+1], bb2 = b1[ch0+2], bb3 = b1[ch0+3];
#pragma unroll
        for (int nt = 0; nt < 4; ++nt) {
            int n = (4*wv + nt)*16 + lr;
            Pk4 pk;
            pk.h[0] = (_Float16)fmaxf(acc[mi][nt][0] + bb0, 0.f);
            pk.h[1] = (_Float16)fmaxf(acc[mi][nt][1] + bb1, 0.f);
            pk.h[2] = (_Float16)fmaxf(acc[mi][nt][2] + bb2, 0.f);
            pk.h[3] = (_Float16)fmaxf(acc[mi][nt][3] + bb3, 0.f);
            *(u64*)&h1T[swz64(n, ch0)] = pk.u;
        }
    }

    // ---- GEMM2: H2[64][256] = W2[64][64] * H1[64][256] (2 k-steps) ----
#pragma unroll
    for (int mi = 0; mi < 4; ++mi)
#pragma unroll
        for (int nt = 0; nt < 4; ++nt) acc[mi][nt] = (f32x4){0.f,0.f,0.f,0.f};
#pragma unroll
    for (int ks = 0; ks < 2; ++ks) {
        int kk = ks*32 + lk*8;
        f16x8 bf[4];
#pragma unroll
        for (int nt = 0; nt < 4; ++nt)
            bf[nt] = *(const f16x8*)&h1T[swz64((4*wv + nt)*16 + lr, kk)];
#pragma unroll
        for (int mi = 0; mi < 4; ++mi) {
            f16x8 af = *(const f16x8*)&W2mh[(mi*16 + lr)*64 + kk];
#pragma unroll
            for (int nt = 0; nt < 4; ++nt)
                acc[mi][nt] = __builtin_amdgcn_mfma_f32_16x16x32_f16(af, bf[nt], acc[mi][nt], 0, 0, 0);
        }
    }
    // epilogue: h2 back into h1T (wave-local, all reads complete in-wave)
#pragma unroll
    for (int mi = 0; mi < 4; ++mi) {
        int ch0 = mi*16 + lk*4;
        float bb0 = b2[ch0], bb1 = b2[ch0+1], bb2 = b2[ch0+2], bb3 = b2[ch0+3];
#pragma unroll
        for (int nt = 0; nt < 4; ++nt) {
            int n = (4*wv + nt)*16 + lr;
            Pk4 pk;
            pk.h[0] = (_Float16)fmaxf(acc[mi][nt][0] + bb0, 0.f);
            pk.h[1] = (_Float16)fmaxf(acc[mi][nt][1] + bb1, 0.f);
            pk.h[2] = (_Float16)fmaxf(acc[mi][nt][2] + bb2, 0.f);
            pk.h[3] = (_Float16)fmaxf(acc[mi][nt][3] + bb3, 0.f);
            *(u64*)&h1T[swz64(n, ch0)] = pk.u;
        }
    }

    // ---- GEMM3: Y[128][256] = W3[128][64] * H2[64][256] + maxpool(32) ----
    f32x4 acc3[8][4];
#pragma unroll
    for (int mi = 0; mi < 8; ++mi)
#pragma unroll
        for (int nt = 0; nt < 4; ++nt) acc3[mi][nt] = (f32x4){0.f,0.f,0.f,0.f};
#pragma unroll
    for (int ks = 0; ks < 2; ++ks) {
        int kk = ks*32 + lk*8;
        f16x8 bf[4];
#pragma unroll
        for (int nt = 0; nt < 4; ++nt)
            bf[nt] = *(const f16x8*)&h1T[swz64((4*wv + nt)*16 + lr, kk)];
#pragma unroll
        for (int mi = 0; mi < 8; ++mi) {
            f16x8 af = *(const f16x8*)&W3mh[(mi*16 + lr)*64 + kk];
#pragma unroll
            for (int nt = 0; nt < 4; ++nt)
                acc3[mi][nt] = __builtin_amdgcn_mfma_f32_16x16x32_f16(af, bf[nt], acc3[mi][nt], 0, 0, 0);
        }
    }
    // maxpool: positions 2wv (tiles 0,1) and 2wv+1 (tiles 2,3); reduce over lr
#pragma unroll
    for (int mi = 0; mi < 8; ++mi) {
        float va[4], vb[4];
#pragma unroll
        for (int r = 0; r < 4; ++r) {
            va[r] = fmaxf(acc3[mi][0][r], acc3[mi][1][r]);
            vb[r] = fmaxf(acc3[mi][2][r], acc3[mi][3][r]);
        }
#pragma unroll
        for (int mk = 1; mk < 16; mk <<= 1) {
#pragma unroll
            for (int r = 0; r < 4; ++r) {
                va[r] = fmaxf(va[r], __shfl_xor(va[r], mk));
                vb[r] = fmaxf(vb[r], __shfl_xor(vb[r], mk));
            }
        }
        if (lr == 0) {
            int ch0 = mi*16 + lk*4;
#pragma unroll
            for (int r = 0; r < 4; ++r) {
                float bias = b3[ch0 + r];
                sout[(ch0 + r)*8 + 2*wv    ] = fmaxf(va[r] + bias, 0.f);
                sout[(ch0 + r)*8 + 2*wv + 1] = fmaxf(vb[r] + bias, 0.f);
            }
        }
    }
    __syncthreads();
    for (int e = tid; e < 128*8; e += 256) {
        int cc = e >> 3, j = e & 7;
        out[((size_t)b*128 + cc)*1024 + m0 + j] = sout[e];
    }
}

// ---------------- K4: knn2 standalone (16.4KB LDS -> 8 blocks/CU) ----------------
__global__ __launch_bounds__(256) void knn2_kernel(
    const float4* __restrict__ p14, const float* __restrict__ p2, int* __restrict__ gidx2)
{
    __shared__ KnnS sm;
    knn_impl<1024, 64, 256>(sm, p14, p2, gidx2, blockIdx.x);
}

// ---------------- K5: mlp2 via fp16 MFMA (R14, verified) ----------------
__global__ __launch_bounds__(256) void mlp2_kernel(
    const float* __restrict__ p1,   // [B,3,1024]
    const float* __restrict__ f1,   // [B,128,1024]
    const float* __restrict__ q2,   // [B,3,256]
    const int*   __restrict__ gidx, // [B,256,64]
    const _Float16* __restrict__ W1h,  // [128][160]
    const _Float16* __restrict__ W2h,  // [128][128]
    const _Float16* __restrict__ W3h,  // [256][128]
    const float* __restrict__ b20, const float* __restrict__ b21, const float* __restrict__ b22,
    float* __restrict__ out)        // feats2 [B,256,256]
{
    __shared__ _Float16 xT[64*168];    // X^T (n-major, stride 168); later h2T (stride 136)
    __shared__ _Float16 h1T[64*136];
    __shared__ int   sgi[64];
    __shared__ float sq[3];

    int tid = threadIdx.x;
    int b = blockIdx.x >> 8, m = blockIdx.x & 255;
    if (tid < 64) sgi[tid] = gidx[((size_t)b*256 + m)*64 + tid];
    else if (tid < 67) sq[tid-64] = q2[((size_t)b*3 + (tid-64))*256 + m];
    __syncthreads();

    union Pk4 { _Float16 h[4]; u64 u; };
    for (int e = tid; e < 40*64; e += 256) {
        int qi = e >> 6, n = e & 63;
        int gi = sgi[n];
        Pk4 pk;
#pragma unroll
        for (int j = 0; j < 4; ++j) {
            int i = qi*4 + j;
            float v;
            if (i < 3)        v = p1[((size_t)b*3 + i)*1024 + gi] - sq[i];
            else if (i < 131) v = f1[((size_t)b*128 + (i-3))*1024 + gi];
            else              v = 0.f;
            pk.h[j] = (_Float16)v;
        }
        *(u64*)&xT[n*168 + qi*4] = pk.u;
    }
    __syncthreads();

    int wv = tid >> 6, l = tid & 63;
    int lr = l & 15, lk = l >> 4;

    // GEMM1: Y1[128][64] = W1[128][160] * X[160][64]
    f32x4 acc[2][4];
#pragma unroll
    for (int mi = 0; mi < 2; ++mi)
#pragma unroll
        for (int nt = 0; nt < 4; ++nt) acc[mi][nt] = (f32x4){0.f,0.f,0.f,0.f};
#pragma unroll
    for (int ks = 0; ks < 5; ++ks) {
        int kk = ks*32 + lk*8;
        f16x8 bf[4];
#pragma unroll
        for (int nt = 0; nt < 4; ++nt)
            bf[nt] = *(const f16x8*)&xT[(nt*16 + lr)*168 + kk];
#pragma unroll
        for (int mi = 0; mi < 2; ++mi) {
            f16x8 af = *(const f16x8*)&W1h[(size_t)((wv*2 + mi)*16 + lr)*160 + kk];
#pragma unroll
            for (int nt = 0; nt < 4; ++nt)
                acc[mi][nt] = __builtin_amdgcn_mfma_f32_16x16x32_f16(af, bf[nt], acc[mi][nt], 0, 0, 0);
        }
    }
#pragma unroll
    for (int mi = 0; mi < 2; ++mi) {
        int ch0 = (wv*2 + mi)*16 + lk*4;
        float bb0 = b20[ch0], bb1 = b20[ch0+1], bb2 = b20[ch0+2], bb3 = b20[ch0+3];
#pragma unroll
        for (int nt = 0; nt < 4; ++nt) {
            int n = nt*16 + lr;
            Pk4 pk;
            pk.h[0] = (_Float16)fmaxf(acc[mi][nt][0] + bb0, 0.f);
            pk.h[1] = (_Float16)fmaxf(acc[mi][nt][1] + bb1, 0.f);
            pk.h[2] = (_Float16)fmaxf(acc[mi][nt][2] + bb2, 0.f);
            pk.h[3] = (_Float16)fmaxf(acc[mi][nt][3] + bb3, 0.f);
            *(u64*)&h1T[n*136 + ch0] = pk.u;
        }
    }
    __syncthreads();

    // GEMM2: Y2 = W2 * H1; h2T into xT region
    _Float16* h2T = xT;
#pragma unroll
    for (int mi = 0; mi < 2; ++mi)
#pragma unroll
        for (int nt = 0; nt < 4; ++nt) acc[mi][nt] = (f32x4){0.f,0.f,0.f,0.f};
#pragma unroll
    for (int ks = 0; ks < 4; ++ks) {
        int kk = ks*32 + lk*8;
        f16x8 bf[4];
#pragma unroll
        for (int nt = 0; nt < 4; ++nt)
            bf[nt] = *(const f16x8*)&h1T[(nt*16 + lr)*136 + kk];
#pragma unroll
        for (int mi = 0; mi < 2; ++mi) {
            f16x8 af = *(const f16x8*)&W2h[(size_t)((wv*2 + mi)*16 + lr)*128 + kk];
#pragma unroll
            for (int nt = 0; nt < 4; ++nt)
                acc[mi][nt] = __builtin_amdgcn_mfma_f32_16x16x32_f16(af, bf[nt], acc[mi][nt], 0, 0, 0);
        }
    }
    __syncthreads();
#pragma unroll
    for (int mi = 0; mi < 2; ++mi) {
        int ch0 = (wv*2 + mi)*16 + lk*4;
        float bb0 = b21[ch0], bb1 = b21[ch0+1], bb2 = b21[ch0+2], bb3 = b21[ch0+3];
#pragma unroll
        for (int nt = 0; nt < 4; ++nt) {
            int n = nt*16 + lr;
            Pk4 pk;
            pk.h[0] = (_Float16)fmaxf(acc[mi][nt][0] + bb0, 0.f);
            pk.h[1] = (_Float16)fmaxf(acc[mi][nt][1] + bb1, 0.f);
            pk.h[2] = (_Float16)fmaxf(acc[mi][nt][2] + bb2, 0.f);
            pk.h[3] = (_Float16)fmaxf(acc[mi][nt][3] + bb3, 0.f);
            *(u64*)&h2T[n*136 + ch0] = pk.u;
        }
    }
    __syncthreads();

    // GEMM3: Y3[256][64] = W3 * H2, maxpool over n
    f32x4 acc3[4][4];
#pragma unroll
    for (int mi = 0; mi < 4; ++mi)
#pragma unroll
        for (int nt = 0; nt < 4; ++nt) acc3[mi][nt] = (f32x4){0.f,0.f,0.f,0.f};
#pragma unroll
    for (int ks = 0; ks < 4; ++ks) {
        int kk = ks*32 + lk*8;
        f16x8 bf[4];
#pragma unroll
        for (int nt = 0; nt < 4; ++nt)
            bf[nt] = *(const f16x8*)&h2T[(nt*16 + lr)*136 + kk];
#pragma unroll
        for (int mi = 0; mi < 4; ++mi) {
            f16x8 af = *(const f16x8*)&W3h[(size_t)((wv*4 + mi)*16 + lr)*128 + kk];
#pragma unroll
            for (int nt = 0; nt < 4; ++nt)
                acc3[mi][nt] = __builtin_amdgcn_mfma_f32_16x16x32_f16(af, bf[nt], acc3[mi][nt], 0, 0, 0);
        }
    }
#pragma unroll
    for (int mi = 0; mi < 4; ++mi) {
        float v0 = acc3[mi][0][0], v1 = acc3[mi][0][1], v2 = acc3[mi][0][2], v3 = acc3[mi][0][3];
#pragma unroll
        for (int nt = 1; nt < 4; ++nt) {
            v0 = fmaxf(v0, acc3[mi][nt][0]);
            v1 = fmaxf(v1, acc3[mi][nt][1]);
            v2 = fmaxf(v2, acc3[mi][nt][2]);
            v3 = fmaxf(v3, acc3[mi][nt][3]);
        }
#pragma unroll
        for (int mk = 1; mk < 16; mk <<= 1) {
            v0 = fmaxf(v0, __shfl_xor(v0, mk));
            v1 = fmaxf(v1, __shfl_xor(v1, mk));
            v2 = fmaxf(v2, __shfl_xor(v2, mk));
            v3 = fmaxf(v3, __shfl_xor(v3, mk));
        }
        if (lr == 0) {
            int ch0 = (wv*4 + mi)*16 + lk*4;
            out[((size_t)b*256 + ch0    )*256 + m] = fmaxf(v0 + b22[ch0],     0.f);
            out[((size_t)b*256 + ch0 + 1)*256 + m] = fmaxf(v1 + b22[ch0 + 1], 0.f);
            out[((size_t)b*256 + ch0 + 2)*256 + m] = fmaxf(v2 + b22[ch0 + 2], 0.f);
            out[((size_t)b*256 + ch0 + 3)*256 + m] = fmaxf(v3 + b22[ch0 + 3], 0.f);
        }
    }
}

// ---------------- launch ----------------
extern "C" void kernel_launch(void* const* d_in, const int* in_sizes, int n_in,
                              void* d_out, int out_size, void* d_ws, size_t ws_size,
                              hipStream_t stream)
{
    const float* pts = (const float*)d_in[0];
    const float* w10 = (const float*)d_in[1];
    const float* g10 = (const float*)d_in[2];
    const float* b10 = (const float*)d_in[3];
    const float* w11 = (const float*)d_in[4];
    const float* g11 = (const float*)d_in[5];
    const float* b11 = (const float*)d_in[6];
    const float* w12 = (const float*)d_in[7];
    const float* g12 = (const float*)d_in[8];
    const float* b12 = (const float*)d_in[9];
    const float* w20 = (const float*)d_in[10];
    const float* g20 = (const float*)d_in[11];
    const float* b20 = (const float*)d_in[12];
    const float* w21 = (const float*)d_in[13];
    const float* g21 = (const float*)d_in[14];
    const float* b21 = (const float*)d_in[15];
    const float* w22 = (const float*)d_in[16];
    const float* g22 = (const float*)d_in[17];
    const float* b22 = (const float*)d_in[18];

    float* out = (float*)d_out;
    char* ws = (char*)d_ws;
    int* gidx1 = (int*)(ws + WS_GIDX1);
    int* gidx2 = (int*)(ws + WS_GIDX2);
    _Float16* W1h  = (_Float16*)(ws + WS_W1H);
    _Float16* W2h  = (_Float16*)(ws + WS_W2H);
    _Float16* W3h  = (_Float16*)(ws + WS_W3H);
    _Float16* W1mh = (_Float16*)(ws + WS_W1MH);
    _Float16* W2mh = (_Float16*)(ws + WS_W2MH);
    _Float16* W3mh = (_Float16*)(ws + WS_W3MH);
    float4* pts4 = (float4*)(ws + WS_PTS4);
    float4* p14  = (float4*)(ws + WS_P14);

    float* p1 = out + O_P1;   // [16,3,1024]
    float* f1 = out + O_F1;   // [16,128,1024]
    float* p2 = out + O_P2;   // [16,3,256]
    float* f2 = out + O_F2;   // [16,256,256]

    // K1: fps1 || prep fp16 weights || pack pts4
    fused1<<<16 + 328 + 64, 256, 0, stream>>>(pts, p1, pts4,
                                              w10, g10, w11, g11, w12, g12,
                                              w20, g20, w21, g21, w22, g22,
                                              W1h, W2h, W3h, W1mh, W2mh, W3mh);
    // K2: fps2 (packs p14) || knn1
    fused2<<<16 + NB * 1024, 256, 0, stream>>>(pts4, p1, p2, gidx1, p14);
    // K3: mlp1 (fp16 MFMA)
    mlp1_mfma<<<NB * 128, 256, 0, stream>>>(pts4, p1, gidx1,
                                            W1mh, W2mh, W3mh, b10, b11, b12, f1);
    // K4: knn2
    knn2_kernel<<<NB * 256, 256, 0, stream>>>(p14, p2, gidx2);
    // K5: mlp2 (fp16 MFMA)
    mlp2_kernel<<<NB * 256, 256, 0, stream>>>(p1, f1, p2, gidx2,
                                              W1h, W2h, W3h, b20, b21, b22, f2);
}